// Round 15
// baseline (290.074 us; speedup 1.0000x reference)
//
#include <hip/hip_runtime.h>
#include <stdint.h>

typedef __attribute__((ext_vector_type(8))) short short8;
typedef __attribute__((ext_vector_type(4))) float f32x4;

__device__ __forceinline__ float bf2f(short s) {
    union { unsigned u; float f; } c;
    c.u = ((unsigned)(unsigned short)s) << 16;
    return c.f;
}
__device__ __forceinline__ short f2bf(float f) {
    union { float f; unsigned u; } c; c.f = f;
    unsigned u = c.u + 0x7fffu + ((c.u >> 16) & 1u);
    return (short)(u >> 16);
}
__device__ __forceinline__ void gll16(const short* g, short* l) {
    __builtin_amdgcn_global_load_lds(
        (const __attribute__((address_space(1))) unsigned int*)g,
        (__attribute__((address_space(3))) unsigned int*)l, 16, 0, 0);
}
#define MFMA(a, b, c) __builtin_amdgcn_mfma_f32_16x16x32_bf16((a), (b), (c), 0, 0, 0)

// ---------------------------------------------------------------- weights cvt
__global__ __launch_bounds__(256) void cvt_w(
    const float* __restrict__ wq, const float* __restrict__ wk,
    const float* __restrict__ wv, const float* __restrict__ wo,
    const float* __restrict__ f1s, const float* __restrict__ f2s,
    const float* __restrict__ f1r, const float* __restrict__ f2r,
    short* __restrict__ dst)
{
    size_t i = ((size_t)blockIdx.x * 256 + threadIdx.x) * 4;
    const float* src; size_t off;
    if (i < 4194304) {
        int seg = (int)(i >> 20);
        src = seg == 0 ? wq : seg == 1 ? wk : seg == 2 ? wv : wo;
        off = i & 1048575;
    } else {
        size_t ii = i - 4194304;
        int seg = (int)(ii >> 22);
        src = seg == 0 ? f1s : seg == 1 ? f2s : seg == 2 ? f1r : f2r;
        off = ii & 4194303;
    }
    float4 v = *(const float4*)(src + off);
    short4 o;
    o.x = f2bf(v.x); o.y = f2bf(v.y); o.z = f2bf(v.z); o.w = f2bf(v.w);
    *(short4*)(dst + i) = o;
}

// ---------------------------------------------------------------- layernorm
// PHASE 0: out_all = LN(x)
// PHASE 1: x1 = x + sum of 2 bf16 WO partials; scatter LN(x1) to out_s/out_r
template<int PHASE>
__global__ __launch_bounds__(256) void ln_k(
    const float* __restrict__ xin, const short* __restrict__ Pw, float* __restrict__ x1out,
    const float* __restrict__ g_sum, const float* __restrict__ b_sum,
    const float* __restrict__ g_reg, const float* __restrict__ b_reg,
    short* __restrict__ out_all, short* __restrict__ out_s, short* __restrict__ out_r)
{
    int row = blockIdx.x;
    int b = row / 2064, t = row - b * 2064;
    int tid = threadIdx.x;
    int c = tid * 4;
    size_t base = (size_t)row * 1024 + c;
    float4 v = *(const float4*)(xin + base);
    if (PHASE == 1) {
#pragma unroll
        for (int z = 0; z < 2; ++z) {
            short4 p = *(const short4*)(Pw + (size_t)z * 4227072 + base);
            v.x += bf2f(p.x); v.y += bf2f(p.y);
            v.z += bf2f(p.z); v.w += bf2f(p.w);
        }
        *(float4*)(x1out + base) = v;
    }
    float s = v.x + v.y + v.z + v.w;
#pragma unroll
    for (int off = 1; off < 64; off <<= 1) s += __shfl_xor(s, off);
    __shared__ float red[8];
    if ((tid & 63) == 0) red[tid >> 6] = s;
    __syncthreads();
    float mu = (red[0] + red[1] + red[2] + red[3]) * (1.0f / 1024.0f);
    float a0 = v.x - mu, a1 = v.y - mu, a2 = v.z - mu, a3 = v.w - mu;
    float qq = a0 * a0 + a1 * a1 + a2 * a2 + a3 * a3;
#pragma unroll
    for (int off = 1; off < 64; off <<= 1) qq += __shfl_xor(qq, off);
    if ((tid & 63) == 0) red[4 + (tid >> 6)] = qq;
    __syncthreads();
    float var = (red[4] + red[5] + red[6] + red[7]) * (1.0f / 1024.0f);
    float rs = rsqrtf(var + 1e-5f);
    const float* g  = (t < 16) ? g_sum : g_reg;
    const float* be = (t < 16) ? b_sum : b_reg;
    short4 o;
    o.x = f2bf(a0 * rs * g[c]     + be[c]);
    o.y = f2bf(a1 * rs * g[c + 1] + be[c + 1]);
    o.z = f2bf(a2 * rs * g[c + 2] + be[c + 2]);
    o.w = f2bf(a3 * rs * g[c + 3] + be[c + 3]);
    short* dst;
    if (PHASE == 0) dst = out_all + (size_t)row * 1024;
    else dst = (t < 16) ? (out_s + ((size_t)b * 16 + t) * 1024)
                        : (out_r + ((size_t)b * 2048 + (t - 16)) * 1024);
    *(short4*)(dst + c) = o;
}

// ---------------------------------------------------------------- GEMM 256x256, BK=64, 2-phase counted-vmcnt
// r15: merged r12's 4 phases into 2 (2 barriers/tile). Ring (8 loads/tile):
//   P0: vmcnt(4) retires H0(t) [oldest 4 of 8]; barrier; stage H0(t+1);
//       read a0[8]+b0..3; 32 MFMA (kk0).
//   P1: vmcnt(4) retires H1(t) [outstanding {H1(t),H0(t+1)}=8]; tail: 0;
//       barrier; stage H1(t+1); read a1[8]+c0..3; 32 MFMA (kk1).
// Never drains mid-loop. Stages issue AFTER the barrier (all waves consumed
// the overwritten half two barriers ago). Conflict-free swizzle unchanged.
template<int MODE>
__global__ __launch_bounds__(512, 2) void gemm8p(
    const short* __restrict__ A, int M, int K, int klen,
    const short* __restrict__ B0, const short* __restrict__ B1, const short* __restrict__ B2,
    const float* __restrict__ bias,
    void* __restrict__ o0, void* __restrict__ o1, void* __restrict__ o2, int seg)
{
    const int tid = threadIdx.x;
    const int w = tid >> 6, l = tid & 63;
    const int lr = l & 15, lh = l >> 4;
    const int m0 = blockIdx.x * 256;
    int ntile = blockIdx.y, nsel = 0;
    const short* B = B0;
    if (MODE == 0) { nsel = ntile >> 2; ntile &= 3; B = nsel == 0 ? B0 : (nsel == 1 ? B1 : B2); }
    const int n0 = ntile * 256;
    const int wm = w >> 2, wn = w & 3;
    const int kbase = blockIdx.z * klen;

    __shared__ __align__(16) short L[2 * 32768];   // 128 KB

    const int srow = tid >> 2;
    const int scb  = (tid & 3) ^ ((srow >> 1) & 3);
    int ar0 = m0 + srow;        if (ar0 > M - 1) ar0 = M - 1;
    int ar1 = m0 + srow + 128;  if (ar1 > M - 1) ar1 = M - 1;
    const short* gA0 = A + (size_t)ar0 * K + kbase + scb * 8;
    const short* gA1 = A + (size_t)ar1 * K + kbase + scb * 8;
    const short* gB0 = B + (size_t)(n0 + srow) * K + kbase + scb * 8;
    const short* gB1 = B + (size_t)(n0 + srow + 128) * K + kbase + scb * 8;
    const int wofs = w * 512;
    const int cbrd = (lh ^ ((lr >> 1) & 3)) * 8;

    f32x4 acc[8][4];
#pragma unroll
    for (int m = 0; m < 8; ++m)
#pragma unroll
        for (int n = 0; n < 4; ++n) acc[m][n] = (f32x4){0.f, 0.f, 0.f, 0.f};

    auto STG = [&](int tt, int s) {          // stage half s of tile tt (A then B, 4 loads)
        const int off = (tt & 1) * 32768 + s * 16384;
        const int gk  = tt * 64 + s * 32;
        gll16(gA0 + gk, L + off + wofs);
        gll16(gA1 + gk, L + off + 4096 + wofs);
        gll16(gB0 + gk, L + off + 8192 + wofs);
        gll16(gB1 + gk, L + off + 12288 + wofs);
    };

    const int nt = klen >> 6;
    STG(0, 0); STG(0, 1);                    // prologue: tile 0 fully staged (8 loads)

    const int arow = wm * 128, brow = wn * 64;

    for (int t = 0; t < nt; ++t) {
        const int buf = (t & 1) * 32768;
        const short* LA0 = L + buf;            // A kk0
        const short* LB0 = L + buf + 8192;     // B kk0
        const short* LA1 = L + buf + 16384;    // A kk1
        const short* LB1 = L + buf + 24576;    // B kk1

        // ---------- P0: kk0, all n
        asm volatile("s_waitcnt vmcnt(4)" ::: "memory");
        __builtin_amdgcn_s_barrier();
        asm volatile("" ::: "memory");
        if (t + 1 < nt) STG(t + 1, 0);
        short8 a0[8];
#pragma unroll
        for (int m = 0; m < 8; ++m)
            a0[m] = *(const short8*)(LA0 + (arow + m * 16 + lr) * 32 + cbrd);
        short8 b0 = *(const short8*)(LB0 + (brow + lr) * 32 + cbrd);
        short8 b1 = *(const short8*)(LB0 + (brow + 16 + lr) * 32 + cbrd);
        short8 b2 = *(const short8*)(LB0 + (brow + 32 + lr) * 32 + cbrd);
        short8 b3 = *(const short8*)(LB0 + (brow + 48 + lr) * 32 + cbrd);
        __builtin_amdgcn_s_setprio(1);
#pragma unroll
        for (int m = 0; m < 8; ++m) {
            acc[m][0] = MFMA(a0[m], b0, acc[m][0]);
            acc[m][1] = MFMA(a0[m], b1, acc[m][1]);
            acc[m][2] = MFMA(a0[m], b2, acc[m][2]);
            acc[m][3] = MFMA(a0[m], b3, acc[m][3]);
        }
        __builtin_amdgcn_s_setprio(0);

        // ---------- P1: kk1, all n
        if (t + 1 < nt) asm volatile("s_waitcnt vmcnt(4)" ::: "memory");
        else            asm volatile("s_waitcnt vmcnt(0)" ::: "memory");
        __builtin_amdgcn_s_barrier();
        asm volatile("" ::: "memory");
        if (t + 1 < nt) STG(t + 1, 1);
        short8 a1[8];
#pragma unroll
        for (int m = 0; m < 8; ++m)
            a1[m] = *(const short8*)(LA1 + (arow + m * 16 + lr) * 32 + cbrd);
        short8 c0 = *(const short8*)(LB1 + (brow + lr) * 32 + cbrd);
        short8 c1 = *(const short8*)(LB1 + (brow + 16 + lr) * 32 + cbrd);
        short8 c2 = *(const short8*)(LB1 + (brow + 32 + lr) * 32 + cbrd);
        short8 c3 = *(const short8*)(LB1 + (brow + 48 + lr) * 32 + cbrd);
        __builtin_amdgcn_s_setprio(1);
#pragma unroll
        for (int m = 0; m < 8; ++m) {
            acc[m][0] = MFMA(a1[m], c0, acc[m][0]);
            acc[m][1] = MFMA(a1[m], c1, acc[m][1]);
            acc[m][2] = MFMA(a1[m], c2, acc[m][2]);
            acc[m][3] = MFMA(a1[m], c3, acc[m][3]);
        }
        __builtin_amdgcn_s_setprio(0);
    }

#pragma unroll
    for (int m = 0; m < 8; ++m) {
#pragma unroll
        for (int n = 0; n < 4; ++n) {
            int gc = n0 + wn * 64 + n * 16 + lr;
#pragma unroll
            for (int j = 0; j < 4; ++j) {
                int gr = m0 + wm * 128 + m * 16 + lh * 4 + j;
                if (gr >= M) continue;
                float val = acc[m][n][j];
                if (MODE == 0) {
                    short* o = (short*)(nsel == 0 ? o0 : (nsel == 1 ? o1 : o2));
                    o[(size_t)gr * 1024 + gc] = f2bf(val);
                } else if (MODE == 2) {
                    val += bias[gc];
                    val = val > 0.f ? val : 0.f;
                    ((short*)o0)[(size_t)gr * 4096 + gc] = f2bf(val);
                } else {
                    short* P = (short*)o0 + (size_t)blockIdx.z * (size_t)seg;
                    P[(size_t)gr * 1024 + gc] = f2bf(val);
                }
            }
        }
    }
}

// ---------------------------------------------------------------- GEMM 128x128 (tiny sum-token cases)
template<int MODE>
__global__ __launch_bounds__(256) void gemm_bt(
    const short* __restrict__ A, int M, int K, int klen,
    const short* __restrict__ B0,
    const float* __restrict__ bias,
    void* __restrict__ o0, int seg)
{
    const int tid = threadIdx.x;
    const int w = tid >> 6, l = tid & 63;
    const int lr = l & 15, lh = l >> 4;
    const int m0 = blockIdx.x * 128;
    const int n0 = blockIdx.y * 128;
    const short* B = B0;
    const int wr = (w >> 1) * 64, wc = (w & 1) * 64;
    const int kbase = blockIdx.z * klen;

    __shared__ __align__(16) short As[2 * 4096];
    __shared__ __align__(16) short Bs[2 * 4096];

    const int srow = w * 32 + (l >> 2);
    const int scol = (((l & 3) ^ ((l >> 3) & 3))) * 8;
    int ar0 = m0 + srow;      if (ar0 > M - 1) ar0 = M - 1;
    int ar1 = m0 + srow + 16; if (ar1 > M - 1) ar1 = M - 1;
    const short* ga0 = A + (size_t)ar0 * K + scol + kbase;
    const short* ga1 = A + (size_t)ar1 * K + scol + kbase;
    const short* gb0 = B + (size_t)(n0 + srow) * K + scol + kbase;
    const short* gb1 = B + (size_t)(n0 + srow + 16) * K + scol + kbase;
    const int lofs = (w * 32) * 32;
    const int cbrd = (lh ^ ((lr >> 1) & 3)) * 8;

    f32x4 acc[4][4];
#pragma unroll
    for (int m = 0; m < 4; ++m)
#pragma unroll
        for (int n = 0; n < 4; ++n) acc[m][n] = (f32x4){0.f, 0.f, 0.f, 0.f};

    auto STAGE = [&](int j, int buf) {
        const int k0 = j * 32;
        short* a = As + buf * 4096 + lofs;
        short* b = Bs + buf * 4096 + lofs;
        gll16(ga0 + k0, a);
        gll16(ga1 + k0, a + 512);
        gll16(gb0 + k0, b);
        gll16(gb1 + k0, b + 512);
    };

    const int nk = klen >> 5;
    STAGE(0, 0);
    for (int t = 0; t < nk; ++t) {
        __syncthreads();
        const int cur = (t & 1);
        if (t + 1 < nk) STAGE(t + 1, cur ^ 1);
        const int co = cur << 12;
        short8 af[4], bfr[4];
#pragma unroll
        for (int m = 0; m < 4; ++m)
            af[m] = *(const short8*)(As + co + (wr + m * 16 + lr) * 32 + cbrd);
#pragma unroll
        for (int n = 0; n < 4; ++n)
            bfr[n] = *(const short8*)(Bs + co + (wc + n * 16 + lr) * 32 + cbrd);
#pragma unroll
        for (int m = 0; m < 4; ++m)
#pragma unroll
            for (int n = 0; n < 4; ++n)
                acc[m][n] = MFMA(af[m], bfr[n], acc[m][n]);
    }

#pragma unroll
    for (int m = 0; m < 4; ++m) {
#pragma unroll
        for (int n = 0; n < 4; ++n) {
            int gc = n0 + wc + n * 16 + lr;
#pragma unroll
            for (int j = 0; j < 4; ++j) {
                int gr = m0 + wr + m * 16 + lh * 4 + j;
                if (gr >= M) continue;
                float val = acc[m][n][j];
                if (MODE == 1) {
                    float* P = (float*)o0 + (size_t)blockIdx.z * (size_t)seg;
                    P[(size_t)gr * 1024 + gc] = val;
                } else {
                    val += bias[gc];
                    val = val > 0.f ? val : 0.f;
                    ((short*)o0)[(size_t)gr * 4096 + gc] = f2bf(val);
                }
            }
        }
    }
}

// ---------------------------------------------------------------- split-K reduces
__global__ __launch_bounds__(256) void reduce_f2reg(
    const float* __restrict__ x1, const short* __restrict__ P,
    const float* __restrict__ bias, float* __restrict__ out)
{
    size_t i = ((size_t)blockIdx.x * 256 + threadIdx.x) * 4;
    int gr = (int)(i >> 10), c = (int)(i & 1023);
    size_t g = (size_t)((gr >> 11) * 2064 + 16 + (gr & 2047)) * 1024 + c;
    float4 r  = *(const float4*)(x1 + g);
    float4 bb = *(const float4*)(bias + c);
    float ox = r.x + bb.x, oy = r.y + bb.y, oz = r.z + bb.z, ow = r.w + bb.w;
#pragma unroll
    for (int z = 0; z < 4; ++z) {
        short4 p = *(const short4*)(P + (size_t)z * 4194304 + i);
        ox += bf2f(p.x); oy += bf2f(p.y); oz += bf2f(p.z); ow += bf2f(p.w);
    }
    float4 o; o.x = ox; o.y = oy; o.z = oz; o.w = ow;
    *(float4*)(out + g) = o;
}

__global__ __launch_bounds__(256) void reduce_f2sum(
    const float* __restrict__ x1, const float* __restrict__ P,
    const float* __restrict__ bias, float* __restrict__ out)
{
    int i = (blockIdx.x * 256 + threadIdx.x) * 4;   // over 32*1024
    int gr = i >> 10, c = i & 1023;
    size_t g = (size_t)((gr >> 4) * 2064 + (gr & 15)) * 1024 + c;
    float4 r  = *(const float4*)(x1 + g);
    float4 bb = *(const float4*)(bias + c);
    float ox = r.x + bb.x, oy = r.y + bb.y, oz = r.z + bb.z, ow = r.w + bb.w;
#pragma unroll
    for (int s = 0; s < 16; ++s) {
        float4 p = *(const float4*)(P + s * 32768 + i);
        ox += p.x; oy += p.y; oz += p.z; ow += p.w;
    }
    float4 o; o.x = ox; o.y = oy; o.z = oz; o.w = ow;
    *(float4*)(out + g) = o;
}

// ---------------------------------------------------------------- chunk attention (reg queries)
__global__ __launch_bounds__(256) void attn_reg(
    const short* __restrict__ q, const short* __restrict__ k,
    const short* __restrict__ v, short* __restrict__ ctx)
{
    __shared__ __align__(16) short Pl[128 * 168];
    __shared__ __align__(16) short Vt[64 * 168];
    short* Kl = Pl;

    const int tid = threadIdx.x;
    const int w = tid >> 6, l = tid & 63, lr = l & 15, lh = l >> 4;
    const int c = blockIdx.x, h = blockIdx.y, b = blockIdx.z;
    const int hc = h * 64;
    const size_t rowq0 = (size_t)b * 2064 + 16 + (size_t)c * 128;

    for (int ch = tid; ch < 1152; ch += 256) {
        int row = ch >> 3, kk = (ch & 7) << 3;
        size_t grow = (row < 16) ? ((size_t)b * 2064 + row) : (rowq0 + row - 16);
        *(int4*)(Kl + row * 72 + kk) = *(const int4*)(k + grow * 1024 + hc + kk);
    }
    for (int ch = tid; ch < 1152; ch += 256) {
        int j = ch % 144, db = ch / 144;
        size_t grow = (j < 16) ? ((size_t)b * 2064 + j) : (rowq0 + j - 16);
        short8 dv = *(const short8*)(v + grow * 1024 + hc + db * 8);
#pragma unroll
        for (int i = 0; i < 8; ++i) Vt[(db * 8 + i) * 168 + j] = dv[i];
    }
    for (int idx = tid; idx < 1024; idx += 256) {
        int d = idx >> 4, jj = 144 + (idx & 15);
        Vt[d * 168 + jj] = 0;
    }
    __syncthreads();

    short8 qf[2][2];
#pragma unroll
    for (int m = 0; m < 2; ++m) {
        size_t grow = rowq0 + w * 32 + m * 16 + lr;
#pragma unroll
        for (int ks = 0; ks < 2; ++ks)
            qf[m][ks] = *(const short8*)(q + grow * 1024 + hc + ks * 32 + lh * 8);
    }

    f32x4 s[2][9];
#pragma unroll
    for (int m = 0; m < 2; ++m)
#pragma unroll
        for (int n = 0; n < 9; ++n) s[m][n] = (f32x4){0.f, 0.f, 0.f, 0.f};
    __builtin_amdgcn_s_setprio(1);
#pragma unroll
    for (int n = 0; n < 9; ++n) {
        const short* kr = Kl + (n * 16 + lr) * 72;
        short8 k0 = *(const short8*)(kr + lh * 8);
        short8 k1 = *(const short8*)(kr + 32 + lh * 8);
        s[0][n] = MFMA(qf[0][0], k0, s[0][n]);
        s[0][n] = MFMA(qf[0][1], k1, s[0][n]);
        s[1][n] = MFMA(qf[1][0], k0, s[1][n]);
        s[1][n] = MFMA(qf[1][1], k1, s[1][n]);
    }
    __builtin_amdgcn_s_setprio(0);

    float inv_[2][4];
#pragma unroll
    for (int m = 0; m < 2; ++m) {
#pragma unroll
        for (int j = 0; j < 4; ++j) {
            int p = w * 32 + m * 16 + lh * 4 + j;
            float best = -1e30f;
            float e[9];
#pragma unroll
            for (int n = 0; n < 9; ++n) {
                int kk = n * 16 + lr;
                bool vis = (kk < 16) ? (kk < c) : (kk - 16 <= p);
                float val = vis ? s[m][n][j] * 0.125f : -1e30f;
                e[n] = val;
                best = fmaxf(best, val);
            }
#pragma unroll
            for (int off = 1; off < 16; off <<= 1) best = fmaxf(best, __shfl_xor(best, off));
            float sm = 0.f;
#pragma unroll
            for (int n = 0; n < 9; ++n) {
                float ex = __expf(e[n] - best);
                s[m][n][j] = ex;
                sm += ex;
            }
#pragma unroll
            for (int off = 1; off < 16; off <<= 1) sm += __shfl_xor(sm, off);
            inv_[m][j] = 1.0f / sm;
        }
    }

    __syncthreads();
#pragma unroll
    for (int m = 0; m < 2; ++m)
#pragma unroll
        for (int n = 0; n < 9; ++n)
#pragma unroll
            for (int j = 0; j < 4; ++j)
                Pl[(w * 32 + m * 16 + lh * 4 + j) * 168 + n * 16 + lr] = f2bf(s[m][n][j]);
    for (int idx = l; idx < 512; idx += 64) {
        int rr = idx >> 4, kkp = 144 + (idx & 15);
        Pl[(w * 32 + rr) * 168 + kkp] = 0;
    }
    __syncthreads();

    f32x4 dacc[2][4];
#pragma unroll
    for (int m = 0; m < 2; ++m)
#pragma unroll
        for (int n = 0; n < 4; ++n) dacc[m][n] = (f32x4){0.f, 0.f, 0.f, 0.f};
#pragma unroll
    for (int ks = 0; ks < 5; ++ks) {
        int kk0 = ks * 32;
        short8 pa[2];
#pragma unroll
        for (int m = 0; m < 2; ++m)
            pa[m] = *(const short8*)(Pl + (w * 32 + m * 16 + lr) * 168 + kk0 + lh * 8);
        __builtin_amdgcn_s_setprio(1);
#pragma unroll
        for (int n = 0; n < 4; ++n) {
            short8 vb = *(const short8*)(Vt + (n * 16 + lr) * 168 + kk0 + lh * 8);
            dacc[0][n] = MFMA(pa[0], vb, dacc[0][n]);
            dacc[1][n] = MFMA(pa[1], vb, dacc[1][n]);
        }
        __builtin_amdgcn_s_setprio(0);
    }

#pragma unroll
    for (int m = 0; m < 2; ++m)
#pragma unroll
        for (int n = 0; n < 4; ++n)
#pragma unroll
            for (int j = 0; j < 4; ++j) {
                int p = w * 32 + m * 16 + lh * 4 + j;
                ctx[(rowq0 + p) * 1024 + hc + n * 16 + lr] = f2bf(dacc[m][n][j] * inv_[m][j]);
            }
}

// ---------------------------------------------------------------- sum-token attention
__global__ __launch_bounds__(64) void attn_sum(
    const short* __restrict__ q, const short* __restrict__ k,
    const short* __restrict__ v, short* __restrict__ ctx)
{
    int idx = blockIdx.x;
    int b = idx >> 8, h = (idx >> 4) & 15, s = idx & 15;
    int l = threadIdx.x;
    int hc = h * 64;
    size_t qrow = (size_t)b * 2064 + s;
    __shared__ float qv[64];
    __shared__ float pp[192];
    qv[l] = bf2f(q[qrow * 1024 + hc + l]);
    __syncthreads();
    float sc[3];
#pragma unroll
    for (int i = 0; i < 3; ++i) {
        int j = l + i * 64;
        float t = -1e30f;
        if (j < 144 && (j >= 16 || j <= s)) {
            size_t kr = (j < 16) ? ((size_t)b * 2064 + j)
                                 : ((size_t)b * 2064 + 16 + (size_t)s * 128 + (j - 16));
            const short* kp = k + kr * 1024 + hc;
            float acc = 0.f;
            for (int d = 0; d < 64; ++d) acc += qv[d] * bf2f(kp[d]);
            t = acc * 0.125f;
        }
        sc[i] = t;
    }
    float mx = fmaxf(sc[0], fmaxf(sc[1], sc[2]));
#pragma unroll
    for (int off = 1; off < 64; off <<= 1) mx = fmaxf(mx, __shfl_xor(mx, off));
    float sm = 0.f;
#pragma unroll
    for (int i = 0; i < 3; ++i) {
        float ex = (sc[i] > -1e29f) ? __expf(sc[i] - mx) : 0.f;
        pp[l + i * 64] = ex;
        sm += ex;
    }
#pragma unroll
    for (int off = 1; off < 64; off <<= 1) sm += __shfl_xor(sm, off);
    __syncthreads();
    float invs = 1.0f / sm;
    float acc = 0.f;
    for (int j = 0; j < 144; ++j) {
        float pj = pp[j];
        size_t vr = (j < 16) ? ((size_t)b * 2064 + j)
                             : ((size_t)b * 2064 + 16 + (size_t)s * 128 + (j - 16));
        acc += pj * bf2f(v[vr * 1024 + hc + l]);
    }
    ctx[qrow * 1024 + hc + l] = f2bf(acc * invs);
}

// ---------------------------------------------------------------- launch
extern "C" void kernel_launch(void* const* d_in, const int* in_sizes, int n_in,
                              void* d_out, int out_size, void* d_ws, size_t ws_size,
                              hipStream_t stream) {
    const float* x    = (const float*)d_in[0];
    const float* wq   = (const float*)d_in[1];
    const float* wk   = (const float*)d_in[2];
    const float* wv   = (const float*)d_in[3];
    const float* wo   = (const float*)d_in[4];
    const float* lsg  = (const float*)d_in[5];
    const float* lsb  = (const float*)d_in[6];
    const float* lrg  = (const float*)d_in[7];
    const float* lrb  = (const float*)d_in[8];
    const float* sf1w = (const float*)d_in[9];
    const float* sf1b = (const float*)d_in[10];
    const float* sf2w = (const float*)d_in[11];
    const float* sf2b = (const float*)d_in[12];
    const float* rf1w = (const float*)d_in[13];
    const float* rf1b = (const float*)d_in[14];
    const float* rf2w = (const float*)d_in[15];
    const float* rf2b = (const float*)d_in[16];
    const float* fsg  = (const float*)d_in[17];
    const float* fsb  = (const float*)d_in[18];
    const float* frg  = (const float*)d_in[19];
    const float* frb  = (const float*)d_in[20];
    float* out = (float*)d_out;

    char* ws = (char*)d_ws;
    // ---- byte-range liveness map ----
    short* wbf   = (short*)ws;
    short* wq_b  = wbf;
    short* wk_b  = wbf + 1048576;
    short* wv_b  = wbf + 2097152;
    short* wo_b  = wbf + 3145728;
    short* f1s_b = wbf + 4194304;
    short* f2s_b = wbf + 8388608;
    short* f1r_b = wbf + 12582912;
    short* f2r_b = wbf + 16777216;
    short* h_all = (short*)(ws + 41943040);   // live 2-3
    short* qb   = (short*)(ws + 50397184);    // live 3-4
    short* kb   = qb + 4227072;
    short* vb   = kb + 4227072;
    short* ctxb = vb + 4227072;               // [75759616, 84213760), live 4-5
    short* Pwo  = (short*)(ws + 41943040);    // bf16 2x4227072 sh, live 5-6
    float* x1   = (float*)(ws + 84213760);    // live 6-9b
    short* h2_reg = (short*)ws;               // [0, 8388608), live 6-7
    short* h2_sum = (short*)(ws + 75759616);  // over dead ctx, live 6-7b
    short* f1_reg = (short*)(ws + 41943040);  // [41943040, 75497472), live 7-9
    short* f1_sum = (short*)(ws + 75825152);  // over dead ctx, live 7b-8
    float* Psum   = (float*)(ws + 8388608);   // over dead f1s_b, live 8-8b
    short* Pf2    = (short*)ws;               // bf16 [0, 33554432), live 9-9b

    // 1. weights -> bf16
    cvt_w<<<20480, 256, 0, stream>>>(wq, wk, wv, wo, sf1w, sf2w, rf1w, rf2w, wbf);
    // 2. pre-attn LN
    ln_k<0><<<4128, 256, 0, stream>>>(x, nullptr, nullptr, lsg, lsb, lrg, lrb,
                                      h_all, nullptr, nullptr);
    // 3. fused QKV (256^2, 2-phase)
    gemm8p<0><<<dim3(17, 12, 1), 512, 0, stream>>>(h_all, 4128, 1024, 1024,
        wq_b, wk_b, wv_b, nullptr, qb, kb, vb, 0);
    // 4. attention
    attn_reg<<<dim3(16, 16, 2), 256, 0, stream>>>(qb, kb, vb, ctxb);
    attn_sum<<<512, 64, 0, stream>>>(qb, kb, vb, ctxb);
    // 5. W_O split-K=2 -> Pwo (bf16 partials)
    gemm8p<3><<<dim3(17, 4, 2), 512, 0, stream>>>(ctxb, 4128, 1024, 512,
        wo_b, nullptr, nullptr, nullptr, Pwo, nullptr, nullptr, 4227072);
    // 6. fused WO-reduce + pre-FFN LN
    ln_k<1><<<4128, 256, 0, stream>>>(x, Pwo, x1, fsg, fsb, frg, frb,
                                      nullptr, h2_sum, h2_reg);
    // 7. FFN1-reg
    gemm8p<2><<<dim3(16, 16, 1), 512, 0, stream>>>(h2_reg, 4096, 1024, 1024,
        f1r_b, nullptr, nullptr, rf1b, f1_reg, nullptr, nullptr, 0);
    // 7b. FFN1-sum
    gemm_bt<2><<<dim3(1, 32, 1), 256, 0, stream>>>(h2_sum, 32, 1024, 1024,
        f1s_b, sf1b, f1_sum, 0);
    // 8. FFN2-sum split-K=16 -> Psum (f32), reduce -> out (sum rows)
    gemm_bt<1><<<dim3(1, 8, 16), 256, 0, stream>>>(f1_sum, 32, 4096, 256,
        f2s_b, nullptr, Psum, 32768);
    reduce_f2sum<<<32, 256, 0, stream>>>(x1, Psum, sf2b, out);
    // 9. FFN2-reg split-K=4 -> Pf2 (bf16 partials)
    gemm8p<3><<<dim3(16, 4, 4), 512, 0, stream>>>(f1_reg, 4096, 4096, 1024,
        f2r_b, nullptr, nullptr, nullptr, Pf2, nullptr, nullptr, 4194304);
    reduce_f2reg<<<4096, 256, 0, stream>>>(x1, Pf2, rf2b, out);
}

// Round 16
// 276.672 us; speedup vs baseline: 1.0484x; 1.0484x over previous
//
#include <hip/hip_runtime.h>
#include <stdint.h>

typedef __attribute__((ext_vector_type(8))) short short8;
typedef __attribute__((ext_vector_type(4))) float f32x4;

__device__ __forceinline__ float bf2f(short s) {
    union { unsigned u; float f; } c;
    c.u = ((unsigned)(unsigned short)s) << 16;
    return c.f;
}
__device__ __forceinline__ short f2bf(float f) {
    union { float f; unsigned u; } c; c.f = f;
    unsigned u = c.u + 0x7fffu + ((c.u >> 16) & 1u);
    return (short)(u >> 16);
}
__device__ __forceinline__ void gll16(const short* g, short* l) {
    __builtin_amdgcn_global_load_lds(
        (const __attribute__((address_space(1))) unsigned int*)g,
        (__attribute__((address_space(3))) unsigned int*)l, 16, 0, 0);
}
#define MFMA(a, b, c) __builtin_amdgcn_mfma_f32_16x16x32_bf16((a), (b), (c), 0, 0, 0)

// ---------------------------------------------------------------- weights cvt
__global__ __launch_bounds__(256) void cvt_w(
    const float* __restrict__ wq, const float* __restrict__ wk,
    const float* __restrict__ wv, const float* __restrict__ wo,
    const float* __restrict__ f1s, const float* __restrict__ f2s,
    const float* __restrict__ f1r, const float* __restrict__ f2r,
    short* __restrict__ dst)
{
    size_t i = ((size_t)blockIdx.x * 256 + threadIdx.x) * 4;
    const float* src; size_t off;
    if (i < 4194304) {
        int seg = (int)(i >> 20);
        src = seg == 0 ? wq : seg == 1 ? wk : seg == 2 ? wv : wo;
        off = i & 1048575;
    } else {
        size_t ii = i - 4194304;
        int seg = (int)(ii >> 22);
        src = seg == 0 ? f1s : seg == 1 ? f2s : seg == 2 ? f1r : f2r;
        off = ii & 4194303;
    }
    float4 v = *(const float4*)(src + off);
    short4 o;
    o.x = f2bf(v.x); o.y = f2bf(v.y); o.z = f2bf(v.z); o.w = f2bf(v.w);
    *(short4*)(dst + i) = o;
}

// ---------------------------------------------------------------- layernorm
// PHASE 0: out_all = LN(x)
// PHASE 1: x1 = x + sum of 2 bf16 WO partials; scatter LN(x1) to out_s/out_r
template<int PHASE>
__global__ __launch_bounds__(256) void ln_k(
    const float* __restrict__ xin, const short* __restrict__ Pw, float* __restrict__ x1out,
    const float* __restrict__ g_sum, const float* __restrict__ b_sum,
    const float* __restrict__ g_reg, const float* __restrict__ b_reg,
    short* __restrict__ out_all, short* __restrict__ out_s, short* __restrict__ out_r)
{
    int row = blockIdx.x;
    int b = row / 2064, t = row - b * 2064;
    int tid = threadIdx.x;
    int c = tid * 4;
    size_t base = (size_t)row * 1024 + c;
    float4 v = *(const float4*)(xin + base);
    if (PHASE == 1) {
#pragma unroll
        for (int z = 0; z < 2; ++z) {
            short4 p = *(const short4*)(Pw + (size_t)z * 4227072 + base);
            v.x += bf2f(p.x); v.y += bf2f(p.y);
            v.z += bf2f(p.z); v.w += bf2f(p.w);
        }
        *(float4*)(x1out + base) = v;
    }
    float s = v.x + v.y + v.z + v.w;
#pragma unroll
    for (int off = 1; off < 64; off <<= 1) s += __shfl_xor(s, off);
    __shared__ float red[8];
    if ((tid & 63) == 0) red[tid >> 6] = s;
    __syncthreads();
    float mu = (red[0] + red[1] + red[2] + red[3]) * (1.0f / 1024.0f);
    float a0 = v.x - mu, a1 = v.y - mu, a2 = v.z - mu, a3 = v.w - mu;
    float qq = a0 * a0 + a1 * a1 + a2 * a2 + a3 * a3;
#pragma unroll
    for (int off = 1; off < 64; off <<= 1) qq += __shfl_xor(qq, off);
    if ((tid & 63) == 0) red[4 + (tid >> 6)] = qq;
    __syncthreads();
    float var = (red[4] + red[5] + red[6] + red[7]) * (1.0f / 1024.0f);
    float rs = rsqrtf(var + 1e-5f);
    const float* g  = (t < 16) ? g_sum : g_reg;
    const float* be = (t < 16) ? b_sum : b_reg;
    short4 o;
    o.x = f2bf(a0 * rs * g[c]     + be[c]);
    o.y = f2bf(a1 * rs * g[c + 1] + be[c + 1]);
    o.z = f2bf(a2 * rs * g[c + 2] + be[c + 2]);
    o.w = f2bf(a3 * rs * g[c + 3] + be[c + 3]);
    short* dst;
    if (PHASE == 0) dst = out_all + (size_t)row * 1024;
    else dst = (t < 16) ? (out_s + ((size_t)b * 16 + t) * 1024)
                        : (out_r + ((size_t)b * 2048 + (t - 16)) * 1024);
    *(short4*)(dst + c) = o;
}

// ---------------------------------------------------------------- GEMM 256x256, BK=64, 4-phase counted-vmcnt
// H1(t)'s wait at ph1 (vmcnt(2): outstanding {H1A(t),H1B(t),H0A(t+1)} = 6,
// retire-to-2 lands H1(t)). ph2/ph3 ds_reads hoisted to ph1-tail / ph2-tail,
// overlapping the following barrier-wait + MFMAs. Ring never drains
// (tail tile: vmcnt(0) at ph1). Conflict-free swizzle pair (r7-verified).
template<int MODE>
__global__ __launch_bounds__(512, 2) void gemm8p(
    const short* __restrict__ A, int M, int K, int klen,
    const short* __restrict__ B0, const short* __restrict__ B1, const short* __restrict__ B2,
    const float* __restrict__ bias,
    void* __restrict__ o0, void* __restrict__ o1, void* __restrict__ o2, int seg)
{
    const int tid = threadIdx.x;
    const int w = tid >> 6, l = tid & 63;
    const int lr = l & 15, lh = l >> 4;
    const int m0 = blockIdx.x * 256;
    int ntile = blockIdx.y, nsel = 0;
    const short* B = B0;
    if (MODE == 0) { nsel = ntile >> 2; ntile &= 3; B = nsel == 0 ? B0 : (nsel == 1 ? B1 : B2); }
    const int n0 = ntile * 256;
    const int wm = w >> 2, wn = w & 3;
    const int kbase = blockIdx.z * klen;

    __shared__ __align__(16) short L[2 * 32768];   // 128 KB

    // staging: thread covers rows (tid>>2) and +128; source colblock pre-swizzled
    const int srow = tid >> 2;
    const int scb  = (tid & 3) ^ ((srow >> 1) & 3);
    int ar0 = m0 + srow;        if (ar0 > M - 1) ar0 = M - 1;
    int ar1 = m0 + srow + 128;  if (ar1 > M - 1) ar1 = M - 1;
    const short* gA0 = A + (size_t)ar0 * K + kbase + scb * 8;
    const short* gA1 = A + (size_t)ar1 * K + kbase + scb * 8;
    const short* gB0 = B + (size_t)(n0 + srow) * K + kbase + scb * 8;
    const short* gB1 = B + (size_t)(n0 + srow + 128) * K + kbase + scb * 8;
    const int wofs = w * 512;                       // wave-uniform LDS base (shorts)
    const int cbrd = (lh ^ ((lr >> 1) & 3)) * 8;    // read-side swizzle (conflict-free)

    f32x4 acc[8][4];
#pragma unroll
    for (int m = 0; m < 8; ++m)
#pragma unroll
        for (int n = 0; n < 4; ++n) acc[m][n] = (f32x4){0.f, 0.f, 0.f, 0.f};

    auto STG = [&](int tt, int s, bool isB) {
        const int off = (tt & 1) * 32768 + s * 16384 + (isB ? 8192 : 0);
        const int gk  = tt * 64 + s * 32;
        if (!isB) {
            gll16(gA0 + gk, L + off + wofs);
            gll16(gA1 + gk, L + off + 4096 + wofs);
        } else {
            gll16(gB0 + gk, L + off + wofs);
            gll16(gB1 + gk, L + off + 4096 + wofs);
        }
    };

    const int nt = klen >> 6;
    STG(0, 0, false); STG(0, 0, true); STG(0, 1, false); STG(0, 1, true);

    const int arow = wm * 128, brow = wn * 64;

    for (int t = 0; t < nt; ++t) {
        const int buf = (t & 1) * 32768;
        const short* LA0 = L + buf;            // A kk0
        const short* LB0 = L + buf + 8192;     // B kk0
        const short* LA1 = L + buf + 16384;    // A kk1
        const short* LB1 = L + buf + 24576;    // B kk1

        // ---------- phase 0: (kk0, n0-1)  [H0(t) becomes ready here]
        asm volatile("s_waitcnt vmcnt(4)" ::: "memory");
        __builtin_amdgcn_s_barrier();
        asm volatile("" ::: "memory");
        if (t + 1 < nt) STG(t + 1, 0, false);
        short8 a0[8];
#pragma unroll
        for (int m = 0; m < 8; ++m)
            a0[m] = *(const short8*)(LA0 + (arow + m * 16 + lr) * 32 + cbrd);
        short8 b0 = *(const short8*)(LB0 + (brow + lr) * 32 + cbrd);
        short8 b1 = *(const short8*)(LB0 + (brow + 16 + lr) * 32 + cbrd);
        __builtin_amdgcn_s_setprio(1);
#pragma unroll
        for (int m = 0; m < 8; ++m) {
            acc[m][0] = MFMA(a0[m], b0, acc[m][0]);
            acc[m][1] = MFMA(a0[m], b1, acc[m][1]);
        }
        __builtin_amdgcn_s_setprio(0);

        // ---------- phase 1: (kk0, n2-3)  [H1(t) becomes ready here — early wait]
        if (t + 1 < nt) asm volatile("s_waitcnt vmcnt(2)" ::: "memory");
        else            asm volatile("s_waitcnt vmcnt(0)" ::: "memory");
        __builtin_amdgcn_s_barrier();
        asm volatile("" ::: "memory");
        if (t + 1 < nt) STG(t + 1, 0, true);
        short8 b2 = *(const short8*)(LB0 + (brow + 32 + lr) * 32 + cbrd);
        short8 b3 = *(const short8*)(LB0 + (brow + 48 + lr) * 32 + cbrd);
        __builtin_amdgcn_s_setprio(1);
#pragma unroll
        for (int m = 0; m < 8; ++m) {
            acc[m][2] = MFMA(a0[m], b2, acc[m][2]);
            acc[m][3] = MFMA(a0[m], b3, acc[m][3]);
        }
        __builtin_amdgcn_s_setprio(0);
        // hoisted H1 reads: valid (all waves passed ph1 barrier => H1(t) landed);
        // they overlap ph2's barrier-wait. H1(t+1) stages go to the OTHER buffer.
        short8 a1[8];
#pragma unroll
        for (int m = 0; m < 8; ++m)
            a1[m] = *(const short8*)(LA1 + (arow + m * 16 + lr) * 32 + cbrd);
        short8 c0 = *(const short8*)(LB1 + (brow + lr) * 32 + cbrd);
        short8 c1 = *(const short8*)(LB1 + (brow + 16 + lr) * 32 + cbrd);

        // ---------- phase 2: (kk1, n0-1)  [operands already in flight/regs]
        __builtin_amdgcn_s_barrier();
        asm volatile("" ::: "memory");
        if (t + 1 < nt) STG(t + 1, 1, false);
        __builtin_amdgcn_s_setprio(1);
#pragma unroll
        for (int m = 0; m < 8; ++m) {
            acc[m][0] = MFMA(a1[m], c0, acc[m][0]);
            acc[m][1] = MFMA(a1[m], c1, acc[m][1]);
        }
        __builtin_amdgcn_s_setprio(0);
        short8 c2 = *(const short8*)(LB1 + (brow + 32 + lr) * 32 + cbrd);
        short8 c3 = *(const short8*)(LB1 + (brow + 48 + lr) * 32 + cbrd);

        // ---------- phase 3: (kk1, n2-3)
        __builtin_amdgcn_s_barrier();
        asm volatile("" ::: "memory");
        if (t + 1 < nt) STG(t + 1, 1, true);
        __builtin_amdgcn_s_setprio(1);
#pragma unroll
        for (int m = 0; m < 8; ++m) {
            acc[m][2] = MFMA(a1[m], c2, acc[m][2]);
            acc[m][3] = MFMA(a1[m], c3, acc[m][3]);
        }
        __builtin_amdgcn_s_setprio(0);
    }

#pragma unroll
    for (int m = 0; m < 8; ++m) {
#pragma unroll
        for (int n = 0; n < 4; ++n) {
            int gc = n0 + wn * 64 + n * 16 + lr;
#pragma unroll
            for (int j = 0; j < 4; ++j) {
                int gr = m0 + wm * 128 + m * 16 + lh * 4 + j;
                if (gr >= M) continue;
                float val = acc[m][n][j];
                if (MODE == 0) {
                    short* o = (short*)(nsel == 0 ? o0 : (nsel == 1 ? o1 : o2));
                    o[(size_t)gr * 1024 + gc] = f2bf(val);
                } else if (MODE == 2) {
                    val += bias[gc];
                    val = val > 0.f ? val : 0.f;
                    ((short*)o0)[(size_t)gr * 4096 + gc] = f2bf(val);
                } else {
                    short* P = (short*)o0 + (size_t)blockIdx.z * (size_t)seg;
                    P[(size_t)gr * 1024 + gc] = f2bf(val);
                }
            }
        }
    }
}

// ---------------------------------------------------------------- GEMM 128x128 (tiny sum-token cases)
template<int MODE>
__global__ __launch_bounds__(256) void gemm_bt(
    const short* __restrict__ A, int M, int K, int klen,
    const short* __restrict__ B0,
    const float* __restrict__ bias,
    void* __restrict__ o0, int seg)
{
    const int tid = threadIdx.x;
    const int w = tid >> 6, l = tid & 63;
    const int lr = l & 15, lh = l >> 4;
    const int m0 = blockIdx.x * 128;
    const int n0 = blockIdx.y * 128;
    const short* B = B0;
    const int wr = (w >> 1) * 64, wc = (w & 1) * 64;
    const int kbase = blockIdx.z * klen;

    __shared__ __align__(16) short As[2 * 4096];
    __shared__ __align__(16) short Bs[2 * 4096];

    const int srow = w * 32 + (l >> 2);
    const int scol = (((l & 3) ^ ((l >> 3) & 3))) * 8;
    int ar0 = m0 + srow;      if (ar0 > M - 1) ar0 = M - 1;
    int ar1 = m0 + srow + 16; if (ar1 > M - 1) ar1 = M - 1;
    const short* ga0 = A + (size_t)ar0 * K + scol + kbase;
    const short* ga1 = A + (size_t)ar1 * K + scol + kbase;
    const short* gb0 = B + (size_t)(n0 + srow) * K + scol + kbase;
    const short* gb1 = B + (size_t)(n0 + srow + 16) * K + scol + kbase;
    const int lofs = (w * 32) * 32;
    const int cbrd = (lh ^ ((lr >> 1) & 3)) * 8;

    f32x4 acc[4][4];
#pragma unroll
    for (int m = 0; m < 4; ++m)
#pragma unroll
        for (int n = 0; n < 4; ++n) acc[m][n] = (f32x4){0.f, 0.f, 0.f, 0.f};

    auto STAGE = [&](int j, int buf) {
        const int k0 = j * 32;
        short* a = As + buf * 4096 + lofs;
        short* b = Bs + buf * 4096 + lofs;
        gll16(ga0 + k0, a);
        gll16(ga1 + k0, a + 512);
        gll16(gb0 + k0, b);
        gll16(gb1 + k0, b + 512);
    };

    const int nk = klen >> 5;
    STAGE(0, 0);
    for (int t = 0; t < nk; ++t) {
        __syncthreads();
        const int cur = (t & 1);
        if (t + 1 < nk) STAGE(t + 1, cur ^ 1);
        const int co = cur << 12;
        short8 af[4], bfr[4];
#pragma unroll
        for (int m = 0; m < 4; ++m)
            af[m] = *(const short8*)(As + co + (wr + m * 16 + lr) * 32 + cbrd);
#pragma unroll
        for (int n = 0; n < 4; ++n)
            bfr[n] = *(const short8*)(Bs + co + (wc + n * 16 + lr) * 32 + cbrd);
#pragma unroll
        for (int m = 0; m < 4; ++m)
#pragma unroll
            for (int n = 0; n < 4; ++n)
                acc[m][n] = MFMA(af[m], bfr[n], acc[m][n]);
    }

#pragma unroll
    for (int m = 0; m < 4; ++m) {
#pragma unroll
        for (int n = 0; n < 4; ++n) {
            int gc = n0 + wc + n * 16 + lr;
#pragma unroll
            for (int j = 0; j < 4; ++j) {
                int gr = m0 + wr + m * 16 + lh * 4 + j;
                if (gr >= M) continue;
                float val = acc[m][n][j];
                if (MODE == 1) {
                    float* P = (float*)o0 + (size_t)blockIdx.z * (size_t)seg;
                    P[(size_t)gr * 1024 + gc] = val;
                } else {
                    val += bias[gc];
                    val = val > 0.f ? val : 0.f;
                    ((short*)o0)[(size_t)gr * 4096 + gc] = f2bf(val);
                }
            }
        }
    }
}

// ---------------------------------------------------------------- split-K reduces
__global__ __launch_bounds__(256) void reduce_f2reg(
    const float* __restrict__ x1, const short* __restrict__ P,
    const float* __restrict__ bias, float* __restrict__ out)
{
    size_t i = ((size_t)blockIdx.x * 256 + threadIdx.x) * 4;
    int gr = (int)(i >> 10), c = (int)(i & 1023);
    size_t g = (size_t)((gr >> 11) * 2064 + 16 + (gr & 2047)) * 1024 + c;
    float4 r  = *(const float4*)(x1 + g);
    float4 bb = *(const float4*)(bias + c);
    float ox = r.x + bb.x, oy = r.y + bb.y, oz = r.z + bb.z, ow = r.w + bb.w;
#pragma unroll
    for (int z = 0; z < 4; ++z) {
        short4 p = *(const short4*)(P + (size_t)z * 4194304 + i);
        ox += bf2f(p.x); oy += bf2f(p.y); oz += bf2f(p.z); ow += bf2f(p.w);
    }
    float4 o; o.x = ox; o.y = oy; o.z = oz; o.w = ow;
    *(float4*)(out + g) = o;
}

__global__ __launch_bounds__(256) void reduce_f2sum(
    const float* __restrict__ x1, const float* __restrict__ P,
    const float* __restrict__ bias, float* __restrict__ out)
{
    int i = (blockIdx.x * 256 + threadIdx.x) * 4;   // over 32*1024
    int gr = i >> 10, c = i & 1023;
    size_t g = (size_t)((gr >> 4) * 2064 + (gr & 15)) * 1024 + c;
    float4 r  = *(const float4*)(x1 + g);
    float4 bb = *(const float4*)(bias + c);
    float ox = r.x + bb.x, oy = r.y + bb.y, oz = r.z + bb.z, ow = r.w + bb.w;
#pragma unroll
    for (int s = 0; s < 16; ++s) {
        float4 p = *(const float4*)(P + s * 32768 + i);
        ox += p.x; oy += p.y; oz += p.z; ow += p.w;
    }
    float4 o; o.x = ox; o.y = oy; o.z = oz; o.w = ow;
    *(float4*)(out + g) = o;
}

// ---------------------------------------------------------------- chunk attention (reg queries)
__global__ __launch_bounds__(256) void attn_reg(
    const short* __restrict__ q, const short* __restrict__ k,
    const short* __restrict__ v, short* __restrict__ ctx)
{
    __shared__ __align__(16) short Pl[128 * 168];
    __shared__ __align__(16) short Vt[64 * 168];
    short* Kl = Pl;

    const int tid = threadIdx.x;
    const int w = tid >> 6, l = tid & 63, lr = l & 15, lh = l >> 4;
    const int c = blockIdx.x, h = blockIdx.y, b = blockIdx.z;
    const int hc = h * 64;
    const size_t rowq0 = (size_t)b * 2064 + 16 + (size_t)c * 128;

    for (int ch = tid; ch < 1152; ch += 256) {
        int row = ch >> 3, kk = (ch & 7) << 3;
        size_t grow = (row < 16) ? ((size_t)b * 2064 + row) : (rowq0 + row - 16);
        *(int4*)(Kl + row * 72 + kk) = *(const int4*)(k + grow * 1024 + hc + kk);
    }
    for (int ch = tid; ch < 1152; ch += 256) {
        int j = ch % 144, db = ch / 144;
        size_t grow = (j < 16) ? ((size_t)b * 2064 + j) : (rowq0 + j - 16);
        short8 dv = *(const short8*)(v + grow * 1024 + hc + db * 8);
#pragma unroll
        for (int i = 0; i < 8; ++i) Vt[(db * 8 + i) * 168 + j] = dv[i];
    }
    for (int idx = tid; idx < 1024; idx += 256) {
        int d = idx >> 4, jj = 144 + (idx & 15);
        Vt[d * 168 + jj] = 0;
    }
    __syncthreads();

    short8 qf[2][2];
#pragma unroll
    for (int m = 0; m < 2; ++m) {
        size_t grow = rowq0 + w * 32 + m * 16 + lr;
#pragma unroll
        for (int ks = 0; ks < 2; ++ks)
            qf[m][ks] = *(const short8*)(q + grow * 1024 + hc + ks * 32 + lh * 8);
    }

    f32x4 s[2][9];
#pragma unroll
    for (int m = 0; m < 2; ++m)
#pragma unroll
        for (int n = 0; n < 9; ++n) s[m][n] = (f32x4){0.f, 0.f, 0.f, 0.f};
    __builtin_amdgcn_s_setprio(1);
#pragma unroll
    for (int n = 0; n < 9; ++n) {
        const short* kr = Kl + (n * 16 + lr) * 72;
        short8 k0 = *(const short8*)(kr + lh * 8);
        short8 k1 = *(const short8*)(kr + 32 + lh * 8);
        s[0][n] = MFMA(qf[0][0], k0, s[0][n]);
        s[0][n] = MFMA(qf[0][1], k1, s[0][n]);
        s[1][n] = MFMA(qf[1][0], k0, s[1][n]);
        s[1][n] = MFMA(qf[1][1], k1, s[1][n]);
    }
    __builtin_amdgcn_s_setprio(0);

    float inv_[2][4];
#pragma unroll
    for (int m = 0; m < 2; ++m) {
#pragma unroll
        for (int j = 0; j < 4; ++j) {
            int p = w * 32 + m * 16 + lh * 4 + j;
            float best = -1e30f;
            float e[9];
#pragma unroll
            for (int n = 0; n < 9; ++n) {
                int kk = n * 16 + lr;
                bool vis = (kk < 16) ? (kk < c) : (kk - 16 <= p);
                float val = vis ? s[m][n][j] * 0.125f : -1e30f;
                e[n] = val;
                best = fmaxf(best, val);
            }
#pragma unroll
            for (int off = 1; off < 16; off <<= 1) best = fmaxf(best, __shfl_xor(best, off));
            float sm = 0.f;
#pragma unroll
            for (int n = 0; n < 9; ++n) {
                float ex = __expf(e[n] - best);
                s[m][n][j] = ex;
                sm += ex;
            }
#pragma unroll
            for (int off = 1; off < 16; off <<= 1) sm += __shfl_xor(sm, off);
            inv_[m][j] = 1.0f / sm;
        }
    }

    __syncthreads();
#pragma unroll
    for (int m = 0; m < 2; ++m)
#pragma unroll
        for (int n = 0; n < 9; ++n)
#pragma unroll
            for (int j = 0; j < 4; ++j)
                Pl[(w * 32 + m * 16 + lh * 4 + j) * 168 + n * 16 + lr] = f2bf(s[m][n][j]);
    for (int idx = l; idx < 512; idx += 64) {
        int rr = idx >> 4, kkp = 144 + (idx & 15);
        Pl[(w * 32 + rr) * 168 + kkp] = 0;
    }
    __syncthreads();

    f32x4 dacc[2][4];
#pragma unroll
    for (int m = 0; m < 2; ++m)
#pragma unroll
        for (int n = 0; n < 4; ++n) dacc[m][n] = (f32x4){0.f, 0.f, 0.f, 0.f};
#pragma unroll
    for (int ks = 0; ks < 5; ++ks) {
        int kk0 = ks * 32;
        short8 pa[2];
#pragma unroll
        for (int m = 0; m < 2; ++m)
            pa[m] = *(const short8*)(Pl + (w * 32 + m * 16 + lr) * 168 + kk0 + lh * 8);
        __builtin_amdgcn_s_setprio(1);
#pragma unroll
        for (int n = 0; n < 4; ++n) {
            short8 vb = *(const short8*)(Vt + (n * 16 + lr) * 168 + kk0 + lh * 8);
            dacc[0][n] = MFMA(pa[0], vb, dacc[0][n]);
            dacc[1][n] = MFMA(pa[1], vb, dacc[1][n]);
        }
        __builtin_amdgcn_s_setprio(0);
    }

#pragma unroll
    for (int m = 0; m < 2; ++m)
#pragma unroll
        for (int n = 0; n < 4; ++n)
#pragma unroll
            for (int j = 0; j < 4; ++j) {
                int p = w * 32 + m * 16 + lh * 4 + j;
                ctx[(rowq0 + p) * 1024 + hc + n * 16 + lr] = f2bf(dacc[m][n][j] * inv_[m][j]);
            }
}

// ---------------------------------------------------------------- sum-token attention
__global__ __launch_bounds__(64) void attn_sum(
    const short* __restrict__ q, const short* __restrict__ k,
    const short* __restrict__ v, short* __restrict__ ctx)
{
    int idx = blockIdx.x;
    int b = idx >> 8, h = (idx >> 4) & 15, s = idx & 15;
    int l = threadIdx.x;
    int hc = h * 64;
    size_t qrow = (size_t)b * 2064 + s;
    __shared__ float qv[64];
    __shared__ float pp[192];
    qv[l] = bf2f(q[qrow * 1024 + hc + l]);
    __syncthreads();
    float sc[3];
#pragma unroll
    for (int i = 0; i < 3; ++i) {
        int j = l + i * 64;
        float t = -1e30f;
        if (j < 144 && (j >= 16 || j <= s)) {
            size_t kr = (j < 16) ? ((size_t)b * 2064 + j)
                                 : ((size_t)b * 2064 + 16 + (size_t)s * 128 + (j - 16));
            const short* kp = k + kr * 1024 + hc;
            float acc = 0.f;
            for (int d = 0; d < 64; ++d) acc += qv[d] * bf2f(kp[d]);
            t = acc * 0.125f;
        }
        sc[i] = t;
    }
    float mx = fmaxf(sc[0], fmaxf(sc[1], sc[2]));
#pragma unroll
    for (int off = 1; off < 64; off <<= 1) mx = fmaxf(mx, __shfl_xor(mx, off));
    float sm = 0.f;
#pragma unroll
    for (int i = 0; i < 3; ++i) {
        float ex = (sc[i] > -1e29f) ? __expf(sc[i] - mx) : 0.f;
        pp[l + i * 64] = ex;
        sm += ex;
    }
#pragma unroll
    for (int off = 1; off < 64; off <<= 1) sm += __shfl_xor(sm, off);
    __syncthreads();
    float invs = 1.0f / sm;
    float acc = 0.f;
    for (int j = 0; j < 144; ++j) {
        float pj = pp[j];
        size_t vr = (j < 16) ? ((size_t)b * 2064 + j)
                             : ((size_t)b * 2064 + 16 + (size_t)s * 128 + (j - 16));
        acc += pj * bf2f(v[vr * 1024 + hc + l]);
    }
    ctx[qrow * 1024 + hc + l] = f2bf(acc * invs);
}

// ---------------------------------------------------------------- launch
extern "C" void kernel_launch(void* const* d_in, const int* in_sizes, int n_in,
                              void* d_out, int out_size, void* d_ws, size_t ws_size,
                              hipStream_t stream) {
    const float* x    = (const float*)d_in[0];
    const float* wq   = (const float*)d_in[1];
    const float* wk   = (const float*)d_in[2];
    const float* wv   = (const float*)d_in[3];
    const float* wo   = (const float*)d_in[4];
    const float* lsg  = (const float*)d_in[5];
    const float* lsb  = (const float*)d_in[6];
    const float* lrg  = (const float*)d_in[7];
    const float* lrb  = (const float*)d_in[8];
    const float* sf1w = (const float*)d_in[9];
    const float* sf1b = (const float*)d_in[10];
    const float* sf2w = (const float*)d_in[11];
    const float* sf2b = (const float*)d_in[12];
    const float* rf1w = (const float*)d_in[13];
    const float* rf1b = (const float*)d_in[14];
    const float* rf2w = (const float*)d_in[15];
    const float* rf2b = (const float*)d_in[16];
    const float* fsg  = (const float*)d_in[17];
    const float* fsb  = (const float*)d_in[18];
    const float* frg  = (const float*)d_in[19];
    const float* frb  = (const float*)d_in[20];
    float* out = (float*)d_out;

    char* ws = (char*)d_ws;
    // ---- byte-range liveness map ----
    short* wbf   = (short*)ws;
    short* wq_b  = wbf;
    short* wk_b  = wbf + 1048576;
    short* wv_b  = wbf + 2097152;
    short* wo_b  = wbf + 3145728;
    short* f1s_b = wbf + 4194304;
    short* f2s_b = wbf + 8388608;
    short* f1r_b = wbf + 12582912;
    short* f2r_b = wbf + 16777216;
    short* h_all = (short*)(ws + 41943040);   // live 2-3
    short* qb   = (short*)(ws + 50397184);    // live 3-4
    short* kb   = qb + 4227072;
    short* vb   = kb + 4227072;
    short* ctxb = vb + 4227072;               // [75759616, 84213760), live 4-5
    short* Pwo  = (short*)(ws + 41943040);    // bf16 2x4227072 sh, live 5-6
    float* x1   = (float*)(ws + 84213760);    // live 6-9b
    short* h2_reg = (short*)ws;               // [0, 8388608), live 6-7
    short* h2_sum = (short*)(ws + 75759616);  // over dead ctx, live 6-7b
    short* f1_reg = (short*)(ws + 41943040);  // [41943040, 75497472), live 7-9
    short* f1_sum = (short*)(ws + 75825152);  // over dead ctx, live 7b-8
    float* Psum   = (float*)(ws + 8388608);   // over dead f1s_b, live 8-8b
    short* Pf2    = (short*)ws;               // bf16 [0, 33554432), live 9-9b

    // 1. weights -> bf16
    cvt_w<<<20480, 256, 0, stream>>>(wq, wk, wv, wo, sf1w, sf2w, rf1w, rf2w, wbf);
    // 2. pre-attn LN
    ln_k<0><<<4128, 256, 0, stream>>>(x, nullptr, nullptr, lsg, lsb, lrg, lrb,
                                      h_all, nullptr, nullptr);
    // 3. fused QKV (256^2, 4-phase)
    gemm8p<0><<<dim3(17, 12, 1), 512, 0, stream>>>(h_all, 4128, 1024, 1024,
        wq_b, wk_b, wv_b, nullptr, qb, kb, vb, 0);
    // 4. attention
    attn_reg<<<dim3(16, 16, 2), 256, 0, stream>>>(qb, kb, vb, ctxb);
    attn_sum<<<512, 64, 0, stream>>>(qb, kb, vb, ctxb);
    // 5. W_O split-K=2 -> Pwo (bf16 partials)
    gemm8p<3><<<dim3(17, 4, 2), 512, 0, stream>>>(ctxb, 4128, 1024, 512,
        wo_b, nullptr, nullptr, nullptr, Pwo, nullptr, nullptr, 4227072);
    // 6. fused WO-reduce + pre-FFN LN
    ln_k<1><<<4128, 256, 0, stream>>>(x, Pwo, x1, fsg, fsb, frg, frb,
                                      nullptr, h2_sum, h2_reg);
    // 7. FFN1-reg
    gemm8p<2><<<dim3(16, 16, 1), 512, 0, stream>>>(h2_reg, 4096, 1024, 1024,
        f1r_b, nullptr, nullptr, rf1b, f1_reg, nullptr, nullptr, 0);
    // 7b. FFN1-sum
    gemm_bt<2><<<dim3(1, 32, 1), 256, 0, stream>>>(h2_sum, 32, 1024, 1024,
        f1s_b, sf1b, f1_sum, 0);
    // 8. FFN2-sum split-K=16 -> Psum (f32), reduce -> out (sum rows)
    gemm_bt<1><<<dim3(1, 8, 16), 256, 0, stream>>>(f1_sum, 32, 4096, 256,
        f2s_b, nullptr, Psum, 32768);
    reduce_f2sum<<<32, 256, 0, stream>>>(x1, Psum, sf2b, out);
    // 9. FFN2-reg split-K=4 -> Pf2 (bf16 partials)
    gemm8p<3><<<dim3(16, 4, 4), 512, 0, stream>>>(f1_reg, 4096, 4096, 1024,
        f2r_b, nullptr, nullptr, nullptr, Pf2, nullptr, nullptr, 4194304);
    reduce_f2reg<<<4096, 256, 0, stream>>>(x1, Pf2, rf2b, out);
}

// Round 17
// 269.673 us; speedup vs baseline: 1.0757x; 1.0260x over previous
//
#include <hip/hip_runtime.h>
#include <stdint.h>

typedef __attribute__((ext_vector_type(8))) short short8;
typedef __attribute__((ext_vector_type(4))) float f32x4;

__device__ __forceinline__ float bf2f(short s) {
    union { unsigned u; float f; } c;
    c.u = ((unsigned)(unsigned short)s) << 16;
    return c.f;
}
__device__ __forceinline__ short f2bf(float f) {
    union { float f; unsigned u; } c; c.f = f;
    unsigned u = c.u + 0x7fffu + ((c.u >> 16) & 1u);
    return (short)(u >> 16);
}
__device__ __forceinline__ void gll16(const short* g, short* l) {
    __builtin_amdgcn_global_load_lds(
        (const __attribute__((address_space(1))) unsigned int*)g,
        (__attribute__((address_space(3))) unsigned int*)l, 16, 0, 0);
}
#define MFMA(a, b, c) __builtin_amdgcn_mfma_f32_16x16x32_bf16((a), (b), (c), 0, 0, 0)

// ---------------------------------------------------------------- fused weights-cvt + pre-attn LN
// blocks [0, 20480): convert 8 f32 weight mats -> bf16 (4 elems/thread)
// blocks [20480, 24608): LN(x) row (blockIdx.x - 20480) -> h_all  (independent work, overlapped)
__global__ __launch_bounds__(256) void cvt_ln(
    const float* __restrict__ wq, const float* __restrict__ wk,
    const float* __restrict__ wv, const float* __restrict__ wo,
    const float* __restrict__ f1s, const float* __restrict__ f2s,
    const float* __restrict__ f1r, const float* __restrict__ f2r,
    short* __restrict__ dst,
    const float* __restrict__ xin,
    const float* __restrict__ g_sum, const float* __restrict__ b_sum,
    const float* __restrict__ g_reg, const float* __restrict__ b_reg,
    short* __restrict__ out_all)
{
    if (blockIdx.x < 20480) {
        size_t i = ((size_t)blockIdx.x * 256 + threadIdx.x) * 4;
        const float* src; size_t off;
        if (i < 4194304) {
            int seg = (int)(i >> 20);
            src = seg == 0 ? wq : seg == 1 ? wk : seg == 2 ? wv : wo;
            off = i & 1048575;
        } else {
            size_t ii = i - 4194304;
            int seg = (int)(ii >> 22);
            src = seg == 0 ? f1s : seg == 1 ? f2s : seg == 2 ? f1r : f2r;
            off = ii & 4194303;
        }
        float4 v = *(const float4*)(src + off);
        short4 o;
        o.x = f2bf(v.x); o.y = f2bf(v.y); o.z = f2bf(v.z); o.w = f2bf(v.w);
        *(short4*)(dst + i) = o;
        return;
    }
    int row = blockIdx.x - 20480;
    int t = row % 2064;
    int tid = threadIdx.x;
    int c = tid * 4;
    size_t base = (size_t)row * 1024 + c;
    float4 v = *(const float4*)(xin + base);
    float s = v.x + v.y + v.z + v.w;
#pragma unroll
    for (int off = 1; off < 64; off <<= 1) s += __shfl_xor(s, off);
    __shared__ float red[8];
    if ((tid & 63) == 0) red[tid >> 6] = s;
    __syncthreads();
    float mu = (red[0] + red[1] + red[2] + red[3]) * (1.0f / 1024.0f);
    float a0 = v.x - mu, a1 = v.y - mu, a2 = v.z - mu, a3 = v.w - mu;
    float qq = a0 * a0 + a1 * a1 + a2 * a2 + a3 * a3;
#pragma unroll
    for (int off = 1; off < 64; off <<= 1) qq += __shfl_xor(qq, off);
    if ((tid & 63) == 0) red[4 + (tid >> 6)] = qq;
    __syncthreads();
    float var = (red[4] + red[5] + red[6] + red[7]) * (1.0f / 1024.0f);
    float rs = rsqrtf(var + 1e-5f);
    const float* g  = (t < 16) ? g_sum : g_reg;
    const float* be = (t < 16) ? b_sum : b_reg;
    short4 o;
    o.x = f2bf(a0 * rs * g[c]     + be[c]);
    o.y = f2bf(a1 * rs * g[c + 1] + be[c + 1]);
    o.z = f2bf(a2 * rs * g[c + 2] + be[c + 2]);
    o.w = f2bf(a3 * rs * g[c + 3] + be[c + 3]);
    *(short4*)(out_all + base + 0) = o;
}

// ---------------------------------------------------------------- layernorm phase 1
// x1 = x + sum of 2 bf16 WO partials; scatter LN(x1) to out_s/out_r
__global__ __launch_bounds__(256) void ln_k1(
    const float* __restrict__ xin, const short* __restrict__ Pw, float* __restrict__ x1out,
    const float* __restrict__ g_sum, const float* __restrict__ b_sum,
    const float* __restrict__ g_reg, const float* __restrict__ b_reg,
    short* __restrict__ out_s, short* __restrict__ out_r)
{
    int row = blockIdx.x;
    int b = row / 2064, t = row - b * 2064;
    int tid = threadIdx.x;
    int c = tid * 4;
    size_t base = (size_t)row * 1024 + c;
    float4 v = *(const float4*)(xin + base);
#pragma unroll
    for (int z = 0; z < 2; ++z) {
        short4 p = *(const short4*)(Pw + (size_t)z * 4227072 + base);
        v.x += bf2f(p.x); v.y += bf2f(p.y);
        v.z += bf2f(p.z); v.w += bf2f(p.w);
    }
    *(float4*)(x1out + base) = v;
    float s = v.x + v.y + v.z + v.w;
#pragma unroll
    for (int off = 1; off < 64; off <<= 1) s += __shfl_xor(s, off);
    __shared__ float red[8];
    if ((tid & 63) == 0) red[tid >> 6] = s;
    __syncthreads();
    float mu = (red[0] + red[1] + red[2] + red[3]) * (1.0f / 1024.0f);
    float a0 = v.x - mu, a1 = v.y - mu, a2 = v.z - mu, a3 = v.w - mu;
    float qq = a0 * a0 + a1 * a1 + a2 * a2 + a3 * a3;
#pragma unroll
    for (int off = 1; off < 64; off <<= 1) qq += __shfl_xor(qq, off);
    if ((tid & 63) == 0) red[4 + (tid >> 6)] = qq;
    __syncthreads();
    float var = (red[4] + red[5] + red[6] + red[7]) * (1.0f / 1024.0f);
    float rs = rsqrtf(var + 1e-5f);
    const float* g  = (t < 16) ? g_sum : g_reg;
    const float* be = (t < 16) ? b_sum : b_reg;
    short4 o;
    o.x = f2bf(a0 * rs * g[c]     + be[c]);
    o.y = f2bf(a1 * rs * g[c + 1] + be[c + 1]);
    o.z = f2bf(a2 * rs * g[c + 2] + be[c + 2]);
    o.w = f2bf(a3 * rs * g[c + 3] + be[c + 3]);
    short* dst = (t < 16) ? (out_s + ((size_t)b * 16 + t) * 1024)
                          : (out_r + ((size_t)b * 2048 + (t - 16)) * 1024);
    *(short4*)(dst + c) = o;
}

// ---------------------------------------------------------------- GEMM 256x256, BK=64, 4-phase counted-vmcnt (r16-verified)
template<int MODE>
__global__ __launch_bounds__(512, 2) void gemm8p(
    const short* __restrict__ A, int M, int K, int klen,
    const short* __restrict__ B0, const short* __restrict__ B1, const short* __restrict__ B2,
    const float* __restrict__ bias,
    void* __restrict__ o0, void* __restrict__ o1, void* __restrict__ o2, int seg)
{
    const int tid = threadIdx.x;
    const int w = tid >> 6, l = tid & 63;
    const int lr = l & 15, lh = l >> 4;
    const int m0 = blockIdx.x * 256;
    int ntile = blockIdx.y, nsel = 0;
    const short* B = B0;
    if (MODE == 0) { nsel = ntile >> 2; ntile &= 3; B = nsel == 0 ? B0 : (nsel == 1 ? B1 : B2); }
    const int n0 = ntile * 256;
    const int wm = w >> 2, wn = w & 3;
    const int kbase = blockIdx.z * klen;

    __shared__ __align__(16) short L[2 * 32768];   // 128 KB

    const int srow = tid >> 2;
    const int scb  = (tid & 3) ^ ((srow >> 1) & 3);
    int ar0 = m0 + srow;        if (ar0 > M - 1) ar0 = M - 1;
    int ar1 = m0 + srow + 128;  if (ar1 > M - 1) ar1 = M - 1;
    const short* gA0 = A + (size_t)ar0 * K + kbase + scb * 8;
    const short* gA1 = A + (size_t)ar1 * K + kbase + scb * 8;
    const short* gB0 = B + (size_t)(n0 + srow) * K + kbase + scb * 8;
    const short* gB1 = B + (size_t)(n0 + srow + 128) * K + kbase + scb * 8;
    const int wofs = w * 512;
    const int cbrd = (lh ^ ((lr >> 1) & 3)) * 8;

    f32x4 acc[8][4];
#pragma unroll
    for (int m = 0; m < 8; ++m)
#pragma unroll
        for (int n = 0; n < 4; ++n) acc[m][n] = (f32x4){0.f, 0.f, 0.f, 0.f};

    auto STG = [&](int tt, int s, bool isB) {
        const int off = (tt & 1) * 32768 + s * 16384 + (isB ? 8192 : 0);
        const int gk  = tt * 64 + s * 32;
        if (!isB) {
            gll16(gA0 + gk, L + off + wofs);
            gll16(gA1 + gk, L + off + 4096 + wofs);
        } else {
            gll16(gB0 + gk, L + off + wofs);
            gll16(gB1 + gk, L + off + 4096 + wofs);
        }
    };

    const int nt = klen >> 6;
    STG(0, 0, false); STG(0, 0, true); STG(0, 1, false); STG(0, 1, true);

    const int arow = wm * 128, brow = wn * 64;

    for (int t = 0; t < nt; ++t) {
        const int buf = (t & 1) * 32768;
        const short* LA0 = L + buf;
        const short* LB0 = L + buf + 8192;
        const short* LA1 = L + buf + 16384;
        const short* LB1 = L + buf + 24576;

        // ph0: (kk0, n0-1)
        asm volatile("s_waitcnt vmcnt(4)" ::: "memory");
        __builtin_amdgcn_s_barrier();
        asm volatile("" ::: "memory");
        if (t + 1 < nt) STG(t + 1, 0, false);
        short8 a0[8];
#pragma unroll
        for (int m = 0; m < 8; ++m)
            a0[m] = *(const short8*)(LA0 + (arow + m * 16 + lr) * 32 + cbrd);
        short8 b0 = *(const short8*)(LB0 + (brow + lr) * 32 + cbrd);
        short8 b1 = *(const short8*)(LB0 + (brow + 16 + lr) * 32 + cbrd);
        __builtin_amdgcn_s_setprio(1);
#pragma unroll
        for (int m = 0; m < 8; ++m) {
            acc[m][0] = MFMA(a0[m], b0, acc[m][0]);
            acc[m][1] = MFMA(a0[m], b1, acc[m][1]);
        }
        __builtin_amdgcn_s_setprio(0);

        // ph1: (kk0, n2-3) — early wait for H1(t)
        if (t + 1 < nt) asm volatile("s_waitcnt vmcnt(2)" ::: "memory");
        else            asm volatile("s_waitcnt vmcnt(0)" ::: "memory");
        __builtin_amdgcn_s_barrier();
        asm volatile("" ::: "memory");
        if (t + 1 < nt) STG(t + 1, 0, true);
        short8 b2 = *(const short8*)(LB0 + (brow + 32 + lr) * 32 + cbrd);
        short8 b3 = *(const short8*)(LB0 + (brow + 48 + lr) * 32 + cbrd);
        __builtin_amdgcn_s_setprio(1);
#pragma unroll
        for (int m = 0; m < 8; ++m) {
            acc[m][2] = MFMA(a0[m], b2, acc[m][2]);
            acc[m][3] = MFMA(a0[m], b3, acc[m][3]);
        }
        __builtin_amdgcn_s_setprio(0);
        short8 a1[8];
#pragma unroll
        for (int m = 0; m < 8; ++m)
            a1[m] = *(const short8*)(LA1 + (arow + m * 16 + lr) * 32 + cbrd);
        short8 c0 = *(const short8*)(LB1 + (brow + lr) * 32 + cbrd);
        short8 c1 = *(const short8*)(LB1 + (brow + 16 + lr) * 32 + cbrd);

        // ph2: (kk1, n0-1)
        __builtin_amdgcn_s_barrier();
        asm volatile("" ::: "memory");
        if (t + 1 < nt) STG(t + 1, 1, false);
        __builtin_amdgcn_s_setprio(1);
#pragma unroll
        for (int m = 0; m < 8; ++m) {
            acc[m][0] = MFMA(a1[m], c0, acc[m][0]);
            acc[m][1] = MFMA(a1[m], c1, acc[m][1]);
        }
        __builtin_amdgcn_s_setprio(0);
        short8 c2 = *(const short8*)(LB1 + (brow + 32 + lr) * 32 + cbrd);
        short8 c3 = *(const short8*)(LB1 + (brow + 48 + lr) * 32 + cbrd);

        // ph3: (kk1, n2-3)
        __builtin_amdgcn_s_barrier();
        asm volatile("" ::: "memory");
        if (t + 1 < nt) STG(t + 1, 1, true);
        __builtin_amdgcn_s_setprio(1);
#pragma unroll
        for (int m = 0; m < 8; ++m) {
            acc[m][2] = MFMA(a1[m], c2, acc[m][2]);
            acc[m][3] = MFMA(a1[m], c3, acc[m][3]);
        }
        __builtin_amdgcn_s_setprio(0);
    }

#pragma unroll
    for (int m = 0; m < 8; ++m) {
#pragma unroll
        for (int n = 0; n < 4; ++n) {
            int gc = n0 + wn * 64 + n * 16 + lr;
#pragma unroll
            for (int j = 0; j < 4; ++j) {
                int gr = m0 + wm * 128 + m * 16 + lh * 4 + j;
                if (gr >= M) continue;
                float val = acc[m][n][j];
                if (MODE == 0) {
                    short* o = (short*)(nsel == 0 ? o0 : (nsel == 1 ? o1 : o2));
                    o[(size_t)gr * 1024 + gc] = f2bf(val);
                } else if (MODE == 2) {
                    val += bias[gc];
                    val = val > 0.f ? val : 0.f;
                    ((short*)o0)[(size_t)gr * 4096 + gc] = f2bf(val);
                } else {
                    short* P = (short*)o0 + (size_t)blockIdx.z * (size_t)seg;
                    P[(size_t)gr * 1024 + gc] = f2bf(val);
                }
            }
        }
    }
}

// ---------------------------------------------------------------- GEMM 128x128 (tiny sum-token cases)
template<int MODE>
__global__ __launch_bounds__(256) void gemm_bt(
    const short* __restrict__ A, int M, int K, int klen,
    const short* __restrict__ B0,
    const float* __restrict__ bias,
    void* __restrict__ o0, int seg)
{
    const int tid = threadIdx.x;
    const int w = tid >> 6, l = tid & 63;
    const int lr = l & 15, lh = l >> 4;
    const int m0 = blockIdx.x * 128;
    const int n0 = blockIdx.y * 128;
    const short* B = B0;
    const int wr = (w >> 1) * 64, wc = (w & 1) * 64;
    const int kbase = blockIdx.z * klen;

    __shared__ __align__(16) short As[2 * 4096];
    __shared__ __align__(16) short Bs[2 * 4096];

    const int srow = w * 32 + (l >> 2);
    const int scol = (((l & 3) ^ ((l >> 3) & 3))) * 8;
    int ar0 = m0 + srow;      if (ar0 > M - 1) ar0 = M - 1;
    int ar1 = m0 + srow + 16; if (ar1 > M - 1) ar1 = M - 1;
    const short* ga0 = A + (size_t)ar0 * K + scol + kbase;
    const short* ga1 = A + (size_t)ar1 * K + scol + kbase;
    const short* gb0 = B + (size_t)(n0 + srow) * K + scol + kbase;
    const short* gb1 = B + (size_t)(n0 + srow + 16) * K + scol + kbase;
    const int lofs = (w * 32) * 32;
    const int cbrd = (lh ^ ((lr >> 1) & 3)) * 8;

    f32x4 acc[4][4];
#pragma unroll
    for (int m = 0; m < 4; ++m)
#pragma unroll
        for (int n = 0; n < 4; ++n) acc[m][n] = (f32x4){0.f, 0.f, 0.f, 0.f};

    auto STAGE = [&](int j, int buf) {
        const int k0 = j * 32;
        short* a = As + buf * 4096 + lofs;
        short* b = Bs + buf * 4096 + lofs;
        gll16(ga0 + k0, a);
        gll16(ga1 + k0, a + 512);
        gll16(gb0 + k0, b);
        gll16(gb1 + k0, b + 512);
    };

    const int nk = klen >> 5;
    STAGE(0, 0);
    for (int t = 0; t < nk; ++t) {
        __syncthreads();
        const int cur = (t & 1);
        if (t + 1 < nk) STAGE(t + 1, cur ^ 1);
        const int co = cur << 12;
        short8 af[4], bfr[4];
#pragma unroll
        for (int m = 0; m < 4; ++m)
            af[m] = *(const short8*)(As + co + (wr + m * 16 + lr) * 32 + cbrd);
#pragma unroll
        for (int n = 0; n < 4; ++n)
            bfr[n] = *(const short8*)(Bs + co + (wc + n * 16 + lr) * 32 + cbrd);
#pragma unroll
        for (int m = 0; m < 4; ++m)
#pragma unroll
            for (int n = 0; n < 4; ++n)
                acc[m][n] = MFMA(af[m], bfr[n], acc[m][n]);
    }

#pragma unroll
    for (int m = 0; m < 4; ++m) {
#pragma unroll
        for (int n = 0; n < 4; ++n) {
            int gc = n0 + wc + n * 16 + lr;
#pragma unroll
            for (int j = 0; j < 4; ++j) {
                int gr = m0 + wr + m * 16 + lh * 4 + j;
                if (gr >= M) continue;
                float val = acc[m][n][j];
                if (MODE == 1) {
                    float* P = (float*)o0 + (size_t)blockIdx.z * (size_t)seg;
                    P[(size_t)gr * 1024 + gc] = val;
                } else {
                    val += bias[gc];
                    val = val > 0.f ? val : 0.f;
                    ((short*)o0)[(size_t)gr * 4096 + gc] = f2bf(val);
                }
            }
        }
    }
}

// ---------------------------------------------------------------- merged split-K reduce (reg + sum rows)
// blocks [0,4096): reg rows — out[g] = x1[g] + sum 4 bf16 Pf2 + rbias
// blocks [4096,4128): sum rows — out[g] = x1[g] + sum 16 f32 Psum + sbias
__global__ __launch_bounds__(256) void reduce_all(
    const float* __restrict__ x1, const short* __restrict__ Pf2,
    const float* __restrict__ Psum,
    const float* __restrict__ rbias, const float* __restrict__ sbias,
    float* __restrict__ out)
{
    if (blockIdx.x < 4096) {
        size_t i = ((size_t)blockIdx.x * 256 + threadIdx.x) * 4;
        int gr = (int)(i >> 10), c = (int)(i & 1023);
        size_t g = (size_t)((gr >> 11) * 2064 + 16 + (gr & 2047)) * 1024 + c;
        float4 r  = *(const float4*)(x1 + g);
        float4 bb = *(const float4*)(rbias + c);
        float ox = r.x + bb.x, oy = r.y + bb.y, oz = r.z + bb.z, ow = r.w + bb.w;
#pragma unroll
        for (int z = 0; z < 4; ++z) {
            short4 p = *(const short4*)(Pf2 + (size_t)z * 4194304 + i);
            ox += bf2f(p.x); oy += bf2f(p.y); oz += bf2f(p.z); ow += bf2f(p.w);
        }
        float4 o; o.x = ox; o.y = oy; o.z = oz; o.w = ow;
        *(float4*)(out + g) = o;
        return;
    }
    int i = ((blockIdx.x - 4096) * 256 + threadIdx.x) * 4;   // over 32*1024
    int gr = i >> 10, c = i & 1023;
    size_t g = (size_t)((gr >> 4) * 2064 + (gr & 15)) * 1024 + c;
    float4 r  = *(const float4*)(x1 + g);
    float4 bb = *(const float4*)(sbias + c);
    float ox = r.x + bb.x, oy = r.y + bb.y, oz = r.z + bb.z, ow = r.w + bb.w;
#pragma unroll
    for (int s = 0; s < 16; ++s) {
        float4 p = *(const float4*)(Psum + s * 32768 + i);
        ox += p.x; oy += p.y; oz += p.z; ow += p.w;
    }
    float4 o; o.x = ox; o.y = oy; o.z = oz; o.w = ow;
    *(float4*)(out + g) = o;
}

// ---------------------------------------------------------------- chunk attention (reg queries)
__global__ __launch_bounds__(256) void attn_reg(
    const short* __restrict__ q, const short* __restrict__ k,
    const short* __restrict__ v, short* __restrict__ ctx)
{
    __shared__ __align__(16) short Pl[128 * 168];
    __shared__ __align__(16) short Vt[64 * 168];
    short* Kl = Pl;

    const int tid = threadIdx.x;
    const int w = tid >> 6, l = tid & 63, lr = l & 15, lh = l >> 4;
    const int c = blockIdx.x, h = blockIdx.y, b = blockIdx.z;
    const int hc = h * 64;
    const size_t rowq0 = (size_t)b * 2064 + 16 + (size_t)c * 128;

    for (int ch = tid; ch < 1152; ch += 256) {
        int row = ch >> 3, kk = (ch & 7) << 3;
        size_t grow = (row < 16) ? ((size_t)b * 2064 + row) : (rowq0 + row - 16);
        *(int4*)(Kl + row * 72 + kk) = *(const int4*)(k + grow * 1024 + hc + kk);
    }
    for (int ch = tid; ch < 1152; ch += 256) {
        int j = ch % 144, db = ch / 144;
        size_t grow = (j < 16) ? ((size_t)b * 2064 + j) : (rowq0 + j - 16);
        short8 dv = *(const short8*)(v + grow * 1024 + hc + db * 8);
#pragma unroll
        for (int i = 0; i < 8; ++i) Vt[(db * 8 + i) * 168 + j] = dv[i];
    }
    for (int idx = tid; idx < 1024; idx += 256) {
        int d = idx >> 4, jj = 144 + (idx & 15);
        Vt[d * 168 + jj] = 0;
    }
    __syncthreads();

    short8 qf[2][2];
#pragma unroll
    for (int m = 0; m < 2; ++m) {
        size_t grow = rowq0 + w * 32 + m * 16 + lr;
#pragma unroll
        for (int ks = 0; ks < 2; ++ks)
            qf[m][ks] = *(const short8*)(q + grow * 1024 + hc + ks * 32 + lh * 8);
    }

    f32x4 s[2][9];
#pragma unroll
    for (int m = 0; m < 2; ++m)
#pragma unroll
        for (int n = 0; n < 9; ++n) s[m][n] = (f32x4){0.f, 0.f, 0.f, 0.f};
    __builtin_amdgcn_s_setprio(1);
#pragma unroll
    for (int n = 0; n < 9; ++n) {
        const short* kr = Kl + (n * 16 + lr) * 72;
        short8 k0 = *(const short8*)(kr + lh * 8);
        short8 k1 = *(const short8*)(kr + 32 + lh * 8);
        s[0][n] = MFMA(qf[0][0], k0, s[0][n]);
        s[0][n] = MFMA(qf[0][1], k1, s[0][n]);
        s[1][n] = MFMA(qf[1][0], k0, s[1][n]);
        s[1][n] = MFMA(qf[1][1], k1, s[1][n]);
    }
    __builtin_amdgcn_s_setprio(0);

    float inv_[2][4];
#pragma unroll
    for (int m = 0; m < 2; ++m) {
#pragma unroll
        for (int j = 0; j < 4; ++j) {
            int p = w * 32 + m * 16 + lh * 4 + j;
            float best = -1e30f;
            float e[9];
#pragma unroll
            for (int n = 0; n < 9; ++n) {
                int kk = n * 16 + lr;
                bool vis = (kk < 16) ? (kk < c) : (kk - 16 <= p);
                float val = vis ? s[m][n][j] * 0.125f : -1e30f;
                e[n] = val;
                best = fmaxf(best, val);
            }
#pragma unroll
            for (int off = 1; off < 16; off <<= 1) best = fmaxf(best, __shfl_xor(best, off));
            float sm = 0.f;
#pragma unroll
            for (int n = 0; n < 9; ++n) {
                float ex = __expf(e[n] - best);
                s[m][n][j] = ex;
                sm += ex;
            }
#pragma unroll
            for (int off = 1; off < 16; off <<= 1) sm += __shfl_xor(sm, off);
            inv_[m][j] = 1.0f / sm;
        }
    }

    __syncthreads();
#pragma unroll
    for (int m = 0; m < 2; ++m)
#pragma unroll
        for (int n = 0; n < 9; ++n)
#pragma unroll
            for (int j = 0; j < 4; ++j)
                Pl[(w * 32 + m * 16 + lh * 4 + j) * 168 + n * 16 + lr] = f2bf(s[m][n][j]);
    for (int idx = l; idx < 512; idx += 64) {
        int rr = idx >> 4, kkp = 144 + (idx & 15);
        Pl[(w * 32 + rr) * 168 + kkp] = 0;
    }
    __syncthreads();

    f32x4 dacc[2][4];
#pragma unroll
    for (int m = 0; m < 2; ++m)
#pragma unroll
        for (int n = 0; n < 4; ++n) dacc[m][n] = (f32x4){0.f, 0.f, 0.f, 0.f};
#pragma unroll
    for (int ks = 0; ks < 5; ++ks) {
        int kk0 = ks * 32;
        short8 pa[2];
#pragma unroll
        for (int m = 0; m < 2; ++m)
            pa[m] = *(const short8*)(Pl + (w * 32 + m * 16 + lr) * 168 + kk0 + lh * 8);
        __builtin_amdgcn_s_setprio(1);
#pragma unroll
        for (int n = 0; n < 4; ++n) {
            short8 vb = *(const short8*)(Vt + (n * 16 + lr) * 168 + kk0 + lh * 8);
            dacc[0][n] = MFMA(pa[0], vb, dacc[0][n]);
            dacc[1][n] = MFMA(pa[1], vb, dacc[1][n]);
        }
        __builtin_amdgcn_s_setprio(0);
    }

#pragma unroll
    for (int m = 0; m < 2; ++m)
#pragma unroll
        for (int n = 0; n < 4; ++n)
#pragma unroll
            for (int j = 0; j < 4; ++j) {
                int p = w * 32 + m * 16 + lh * 4 + j;
                ctx[(rowq0 + p) * 1024 + hc + n * 16 + lr] = f2bf(dacc[m][n][j] * inv_[m][j]);
            }
}

// ---------------------------------------------------------------- sum-token attention
__global__ __launch_bounds__(64) void attn_sum(
    const short* __restrict__ q, const short* __restrict__ k,
    const short* __restrict__ v, short* __restrict__ ctx)
{
    int idx = blockIdx.x;
    int b = idx >> 8, h = (idx >> 4) & 15, s = idx & 15;
    int l = threadIdx.x;
    int hc = h * 64;
    size_t qrow = (size_t)b * 2064 + s;
    __shared__ float qv[64];
    __shared__ float pp[192];
    qv[l] = bf2f(q[qrow * 1024 + hc + l]);
    __syncthreads();
    float sc[3];
#pragma unroll
    for (int i = 0; i < 3; ++i) {
        int j = l + i * 64;
        float t = -1e30f;
        if (j < 144 && (j >= 16 || j <= s)) {
            size_t kr = (j < 16) ? ((size_t)b * 2064 + j)
                                 : ((size_t)b * 2064 + 16 + (size_t)s * 128 + (j - 16));
            const short* kp = k + kr * 1024 + hc;
            float acc = 0.f;
            for (int d = 0; d < 64; ++d) acc += qv[d] * bf2f(kp[d]);
            t = acc * 0.125f;
        }
        sc[i] = t;
    }
    float mx = fmaxf(sc[0], fmaxf(sc[1], sc[2]));
#pragma unroll
    for (int off = 1; off < 64; off <<= 1) mx = fmaxf(mx, __shfl_xor(mx, off));
    float sm = 0.f;
#pragma unroll
    for (int i = 0; i < 3; ++i) {
        float ex = (sc[i] > -1e29f) ? __expf(sc[i] - mx) : 0.f;
        pp[l + i * 64] = ex;
        sm += ex;
    }
#pragma unroll
    for (int off = 1; off < 64; off <<= 1) sm += __shfl_xor(sm, off);
    __syncthreads();
    float invs = 1.0f / sm;
    float acc = 0.f;
    for (int j = 0; j < 144; ++j) {
        float pj = pp[j];
        size_t vr = (j < 16) ? ((size_t)b * 2064 + j)
                             : ((size_t)b * 2064 + 16 + (size_t)s * 128 + (j - 16));
        acc += pj * bf2f(v[vr * 1024 + hc + l]);
    }
    ctx[qrow * 1024 + hc + l] = f2bf(acc * invs);
}

// ---------------------------------------------------------------- launch
extern "C" void kernel_launch(void* const* d_in, const int* in_sizes, int n_in,
                              void* d_out, int out_size, void* d_ws, size_t ws_size,
                              hipStream_t stream) {
    const float* x    = (const float*)d_in[0];
    const float* wq   = (const float*)d_in[1];
    const float* wk   = (const float*)d_in[2];
    const float* wv   = (const float*)d_in[3];
    const float* wo   = (const float*)d_in[4];
    const float* lsg  = (const float*)d_in[5];
    const float* lsb  = (const float*)d_in[6];
    const float* lrg  = (const float*)d_in[7];
    const float* lrb  = (const float*)d_in[8];
    const float* sf1w = (const float*)d_in[9];
    const float* sf1b = (const float*)d_in[10];
    const float* sf2w = (const float*)d_in[11];
    const float* sf2b = (const float*)d_in[12];
    const float* rf1w = (const float*)d_in[13];
    const float* rf1b = (const float*)d_in[14];
    const float* rf2w = (const float*)d_in[15];
    const float* rf2b = (const float*)d_in[16];
    const float* fsg  = (const float*)d_in[17];
    const float* fsb  = (const float*)d_in[18];
    const float* frg  = (const float*)d_in[19];
    const float* frb  = (const float*)d_in[20];
    float* out = (float*)d_out;

    char* ws = (char*)d_ws;
    // ---- byte-range liveness map ----
    short* wbf   = (short*)ws;
    short* wq_b  = wbf;
    short* wk_b  = wbf + 1048576;
    short* wv_b  = wbf + 2097152;
    short* wo_b  = wbf + 3145728;
    short* f1s_b = wbf + 4194304;
    short* f2s_b = wbf + 8388608;
    short* f1r_b = wbf + 12582912;
    short* f2r_b = wbf + 16777216;
    short* h_all = (short*)(ws + 41943040);   // live 1-3
    short* qb   = (short*)(ws + 50397184);    // live 3-4
    short* kb   = qb + 4227072;
    short* vb   = kb + 4227072;
    short* ctxb = vb + 4227072;               // [75759616, 84213760), live 4-5
    short* Pwo  = (short*)(ws + 41943040);    // bf16 2x4227072 sh, live 5-6
    float* x1   = (float*)(ws + 84213760);    // live 6-end
    short* h2_reg = (short*)ws;               // [0, 8388608), live 6-7
    short* h2_sum = (short*)(ws + 75759616);  // [75759616, 75825152) over dead ctx, live 6-7b
    short* f1_reg = (short*)(ws + 41943040);  // [41943040, 75497472), live 7-9
    short* f1_sum = (short*)(ws + 75825152);  // [75825152, 76087296) over dead ctx, live 7b-8
    float* Psum   = (float*)(ws + 76087296);  // f32 2MB [76087296, 78184448) over dead ctx,
                                              // live 8 -> final reduce (clear of Pf2/x1/f1_reg)
    short* Pf2    = (short*)ws;               // bf16 [0, 33554432), live 9 -> final reduce

    // 1. fused weights->bf16 + pre-attn LN (independent, one dispatch)
    cvt_ln<<<24608, 256, 0, stream>>>(wq, wk, wv, wo, sf1w, sf2w, rf1w, rf2w, wbf,
                                      x, lsg, lsb, lrg, lrb, h_all);
    // 3. fused QKV (256^2, 4-phase)
    gemm8p<0><<<dim3(17, 12, 1), 512, 0, stream>>>(h_all, 4128, 1024, 1024,
        wq_b, wk_b, wv_b, nullptr, qb, kb, vb, 0);
    // 4. attention
    attn_reg<<<dim3(16, 16, 2), 256, 0, stream>>>(qb, kb, vb, ctxb);
    attn_sum<<<512, 64, 0, stream>>>(qb, kb, vb, ctxb);
    // 5. W_O split-K=2 -> Pwo (bf16 partials)
    gemm8p<3><<<dim3(17, 4, 2), 512, 0, stream>>>(ctxb, 4128, 1024, 512,
        wo_b, nullptr, nullptr, nullptr, Pwo, nullptr, nullptr, 4227072);
    // 6. fused WO-reduce + pre-FFN LN
    ln_k1<<<4128, 256, 0, stream>>>(x, Pwo, x1, fsg, fsb, frg, frb,
                                    h2_sum, h2_reg);
    // 7b. FFN1-sum (issued before FFN1-reg: tiny, fills in)
    gemm_bt<2><<<dim3(1, 32, 1), 256, 0, stream>>>(h2_sum, 32, 1024, 1024,
        f1s_b, sf1b, f1_sum, 0);
    // 7. FFN1-reg
    gemm8p<2><<<dim3(16, 16, 1), 512, 0, stream>>>(h2_reg, 4096, 1024, 1024,
        f1r_b, nullptr, nullptr, rf1b, f1_reg, nullptr, nullptr, 0);
    // 8. FFN2-sum split-K=16 -> Psum (f32, relocated clear of Pf2)
    gemm_bt<1><<<dim3(1, 8, 16), 256, 0, stream>>>(f1_sum, 32, 4096, 256,
        f2s_b, nullptr, Psum, 32768);
    // 9. FFN2-reg split-K=4 -> Pf2 (bf16 partials)
    gemm8p<3><<<dim3(16, 4, 4), 512, 0, stream>>>(f1_reg, 4096, 4096, 1024,
        f2r_b, nullptr, nullptr, nullptr, Pf2, nullptr, nullptr, 4194304);
    // 10. merged reduce: reg rows (Pf2) + sum rows (Psum) -> out
    reduce_all<<<4128, 256, 0, stream>>>(x1, Pf2, Psum, rf2b, sf2b, out);
}

// Round 19
// 269.573 us; speedup vs baseline: 1.0761x; 1.0004x over previous
//
#include <hip/hip_runtime.h>
#include <stdint.h>

typedef __attribute__((ext_vector_type(8))) short short8;
typedef __attribute__((ext_vector_type(4))) float f32x4;

__device__ __forceinline__ float bf2f(short s) {
    union { unsigned u; float f; } c;
    c.u = ((unsigned)(unsigned short)s) << 16;
    return c.f;
}
__device__ __forceinline__ short f2bf(float f) {
    union { float f; unsigned u; } c; c.f = f;
    unsigned u = c.u + 0x7fffu + ((c.u >> 16) & 1u);
    return (short)(u >> 16);
}
__device__ __forceinline__ void gll16(const short* g, short* l) {
    __builtin_amdgcn_global_load_lds(
        (const __attribute__((address_space(1))) unsigned int*)g,
        (__attribute__((address_space(3))) unsigned int*)l, 16, 0, 0);
}
#define MFMA(a, b, c) __builtin_amdgcn_mfma_f32_16x16x32_bf16((a), (b), (c), 0, 0, 0)

// ---------------------------------------------------------------- fused weights-cvt + pre-attn LN
__global__ __launch_bounds__(256) void cvt_ln(
    const float* __restrict__ wq, const float* __restrict__ wk,
    const float* __restrict__ wv, const float* __restrict__ wo,
    const float* __restrict__ f1s, const float* __restrict__ f2s,
    const float* __restrict__ f1r, const float* __restrict__ f2r,
    short* __restrict__ dst,
    const float* __restrict__ xin,
    const float* __restrict__ g_sum, const float* __restrict__ b_sum,
    const float* __restrict__ g_reg, const float* __restrict__ b_reg,
    short* __restrict__ out_all)
{
    if (blockIdx.x < 20480) {
        size_t i = ((size_t)blockIdx.x * 256 + threadIdx.x) * 4;
        const float* src; size_t off;
        if (i < 4194304) {
            int seg = (int)(i >> 20);
            src = seg == 0 ? wq : seg == 1 ? wk : seg == 2 ? wv : wo;
            off = i & 1048575;
        } else {
            size_t ii = i - 4194304;
            int seg = (int)(ii >> 22);
            src = seg == 0 ? f1s : seg == 1 ? f2s : seg == 2 ? f1r : f2r;
            off = ii & 4194303;
        }
        float4 v = *(const float4*)(src + off);
        short4 o;
        o.x = f2bf(v.x); o.y = f2bf(v.y); o.z = f2bf(v.z); o.w = f2bf(v.w);
        *(short4*)(dst + i) = o;
        return;
    }
    int row = blockIdx.x - 20480;
    int t = row % 2064;
    int tid = threadIdx.x;
    int c = tid * 4;
    size_t base = (size_t)row * 1024 + c;
    float4 v = *(const float4*)(xin + base);
    float s = v.x + v.y + v.z + v.w;
#pragma unroll
    for (int off = 1; off < 64; off <<= 1) s += __shfl_xor(s, off);
    __shared__ float red[8];
    if ((tid & 63) == 0) red[tid >> 6] = s;
    __syncthreads();
    float mu = (red[0] + red[1] + red[2] + red[3]) * (1.0f / 1024.0f);
    float a0 = v.x - mu, a1 = v.y - mu, a2 = v.z - mu, a3 = v.w - mu;
    float qq = a0 * a0 + a1 * a1 + a2 * a2 + a3 * a3;
#pragma unroll
    for (int off = 1; off < 64; off <<= 1) qq += __shfl_xor(qq, off);
    if ((tid & 63) == 0) red[4 + (tid >> 6)] = qq;
    __syncthreads();
    float var = (red[4] + red[5] + red[6] + red[7]) * (1.0f / 1024.0f);
    float rs = rsqrtf(var + 1e-5f);
    const float* g  = (t < 16) ? g_sum : g_reg;
    const float* be = (t < 16) ? b_sum : b_reg;
    short4 o;
    o.x = f2bf(a0 * rs * g[c]     + be[c]);
    o.y = f2bf(a1 * rs * g[c + 1] + be[c + 1]);
    o.z = f2bf(a2 * rs * g[c + 2] + be[c + 2]);
    o.w = f2bf(a3 * rs * g[c + 3] + be[c + 3]);
    *(short4*)(out_all + base) = o;
}

// ---------------------------------------------------------------- layernorm phase 1
__global__ __launch_bounds__(256) void ln_k1(
    const float* __restrict__ xin, const short* __restrict__ Pw, float* __restrict__ x1out,
    const float* __restrict__ g_sum, const float* __restrict__ b_sum,
    const float* __restrict__ g_reg, const float* __restrict__ b_reg,
    short* __restrict__ out_s, short* __restrict__ out_r)
{
    int row = blockIdx.x;
    int b = row / 2064, t = row - b * 2064;
    int tid = threadIdx.x;
    int c = tid * 4;
    size_t base = (size_t)row * 1024 + c;
    float4 v = *(const float4*)(xin + base);
#pragma unroll
    for (int z = 0; z < 2; ++z) {
        short4 p = *(const short4*)(Pw + (size_t)z * 4227072 + base);
        v.x += bf2f(p.x); v.y += bf2f(p.y);
        v.z += bf2f(p.z); v.w += bf2f(p.w);
    }
    *(float4*)(x1out + base) = v;
    float s = v.x + v.y + v.z + v.w;
#pragma unroll
    for (int off = 1; off < 64; off <<= 1) s += __shfl_xor(s, off);
    __shared__ float red[8];
    if ((tid & 63) == 0) red[tid >> 6] = s;
    __syncthreads();
    float mu = (red[0] + red[1] + red[2] + red[3]) * (1.0f / 1024.0f);
    float a0 = v.x - mu, a1 = v.y - mu, a2 = v.z - mu, a3 = v.w - mu;
    float qq = a0 * a0 + a1 * a1 + a2 * a2 + a3 * a3;
#pragma unroll
    for (int off = 1; off < 64; off <<= 1) qq += __shfl_xor(qq, off);
    if ((tid & 63) == 0) red[4 + (tid >> 6)] = qq;
    __syncthreads();
    float var = (red[4] + red[5] + red[6] + red[7]) * (1.0f / 1024.0f);
    float rs = rsqrtf(var + 1e-5f);
    const float* g  = (t < 16) ? g_sum : g_reg;
    const float* be = (t < 16) ? b_sum : b_reg;
    short4 o;
    o.x = f2bf(a0 * rs * g[c]     + be[c]);
    o.y = f2bf(a1 * rs * g[c + 1] + be[c + 1]);
    o.z = f2bf(a2 * rs * g[c + 2] + be[c + 2]);
    o.w = f2bf(a3 * rs * g[c + 3] + be[c + 3]);
    short* dst = (t < 16) ? (out_s + ((size_t)b * 16 + t) * 1024)
                          : (out_r + ((size_t)b * 2048 + (t - 16)) * 1024);
    *(short4*)(dst + c) = o;
}

// ---------------------------------------------------------------- GEMM 256x256, BK=64, 4-phase counted-vmcnt (r16-verified)
template<int MODE>
__global__ __launch_bounds__(512, 2) void gemm8p(
    const short* __restrict__ A, int M, int K, int klen,
    const short* __restrict__ B0, const short* __restrict__ B1, const short* __restrict__ B2,
    const float* __restrict__ bias,
    void* __restrict__ o0, void* __restrict__ o1, void* __restrict__ o2, int seg)
{
    const int tid = threadIdx.x;
    const int w = tid >> 6, l = tid & 63;
    const int lr = l & 15, lh = l >> 4;
    const int m0 = blockIdx.x * 256;
    int ntile = blockIdx.y, nsel = 0;
    const short* B = B0;
    if (MODE == 0) { nsel = ntile >> 2; ntile &= 3; B = nsel == 0 ? B0 : (nsel == 1 ? B1 : B2); }
    const int n0 = ntile * 256;
    const int wm = w >> 2, wn = w & 3;
    const int kbase = blockIdx.z * klen;

    __shared__ __align__(16) short L[2 * 32768];

    const int srow = tid >> 2;
    const int scb  = (tid & 3) ^ ((srow >> 1) & 3);
    int ar0 = m0 + srow;        if (ar0 > M - 1) ar0 = M - 1;
    int ar1 = m0 + srow + 128;  if (ar1 > M - 1) ar1 = M - 1;
    const short* gA0 = A + (size_t)ar0 * K + kbase + scb * 8;
    const short* gA1 = A + (size_t)ar1 * K + kbase + scb * 8;
    const short* gB0 = B + (size_t)(n0 + srow) * K + kbase + scb * 8;
    const short* gB1 = B + (size_t)(n0 + srow + 128) * K + kbase + scb * 8;
    const int wofs = w * 512;
    const int cbrd = (lh ^ ((lr >> 1) & 3)) * 8;

    f32x4 acc[8][4];
#pragma unroll
    for (int m = 0; m < 8; ++m)
#pragma unroll
        for (int n = 0; n < 4; ++n) acc[m][n] = (f32x4){0.f, 0.f, 0.f, 0.f};

    auto STG = [&](int tt, int s, bool isB) {
        const int off = (tt & 1) * 32768 + s * 16384 + (isB ? 8192 : 0);
        const int gk  = tt * 64 + s * 32;
        if (!isB) {
            gll16(gA0 + gk, L + off + wofs);
            gll16(gA1 + gk, L + off + 4096 + wofs);
        } else {
            gll16(gB0 + gk, L + off + wofs);
            gll16(gB1 + gk, L + off + 4096 + wofs);
        }
    };

    const int nt = klen >> 6;
    STG(0, 0, false); STG(0, 0, true); STG(0, 1, false); STG(0, 1, true);

    const int arow = wm * 128, brow = wn * 64;

    for (int t = 0; t < nt; ++t) {
        const int buf = (t & 1) * 32768;
        const short* LA0 = L + buf;
        const short* LB0 = L + buf + 8192;
        const short* LA1 = L + buf + 16384;
        const short* LB1 = L + buf + 24576;

        asm volatile("s_waitcnt vmcnt(4)" ::: "memory");
        __builtin_amdgcn_s_barrier();
        asm volatile("" ::: "memory");
        if (t + 1 < nt) STG(t + 1, 0, false);
        short8 a0[8];
#pragma unroll
        for (int m = 0; m < 8; ++m)
            a0[m] = *(const short8*)(LA0 + (arow + m * 16 + lr) * 32 + cbrd);
        short8 b0 = *(const short8*)(LB0 + (brow + lr) * 32 + cbrd);
        short8 b1 = *(const short8*)(LB0 + (brow + 16 + lr) * 32 + cbrd);
        __builtin_amdgcn_s_setprio(1);
#pragma unroll
        for (int m = 0; m < 8; ++m) {
            acc[m][0] = MFMA(a0[m], b0, acc[m][0]);
            acc[m][1] = MFMA(a0[m], b1, acc[m][1]);
        }
        __builtin_amdgcn_s_setprio(0);

        if (t + 1 < nt) asm volatile("s_waitcnt vmcnt(2)" ::: "memory");
        else            asm volatile("s_waitcnt vmcnt(0)" ::: "memory");
        __builtin_amdgcn_s_barrier();
        asm volatile("" ::: "memory");
        if (t + 1 < nt) STG(t + 1, 0, true);
        short8 b2 = *(const short8*)(LB0 + (brow + 32 + lr) * 32 + cbrd);
        short8 b3 = *(const short8*)(LB0 + (brow + 48 + lr) * 32 + cbrd);
        __builtin_amdgcn_s_setprio(1);
#pragma unroll
        for (int m = 0; m < 8; ++m) {
            acc[m][2] = MFMA(a0[m], b2, acc[m][2]);
            acc[m][3] = MFMA(a0[m], b3, acc[m][3]);
        }
        __builtin_amdgcn_s_setprio(0);
        short8 a1[8];
#pragma unroll
        for (int m = 0; m < 8; ++m)
            a1[m] = *(const short8*)(LA1 + (arow + m * 16 + lr) * 32 + cbrd);
        short8 c0 = *(const short8*)(LB1 + (brow + lr) * 32 + cbrd);
        short8 c1 = *(const short8*)(LB1 + (brow + 16 + lr) * 32 + cbrd);

        __builtin_amdgcn_s_barrier();
        asm volatile("" ::: "memory");
        if (t + 1 < nt) STG(t + 1, 1, false);
        __builtin_amdgcn_s_setprio(1);
#pragma unroll
        for (int m = 0; m < 8; ++m) {
            acc[m][0] = MFMA(a1[m], c0, acc[m][0]);
            acc[m][1] = MFMA(a1[m], c1, acc[m][1]);
        }
        __builtin_amdgcn_s_setprio(0);
        short8 c2 = *(const short8*)(LB1 + (brow + 32 + lr) * 32 + cbrd);
        short8 c3 = *(const short8*)(LB1 + (brow + 48 + lr) * 32 + cbrd);

        __builtin_amdgcn_s_barrier();
        asm volatile("" ::: "memory");
        if (t + 1 < nt) STG(t + 1, 1, true);
        __builtin_amdgcn_s_setprio(1);
#pragma unroll
        for (int m = 0; m < 8; ++m) {
            acc[m][2] = MFMA(a1[m], c2, acc[m][2]);
            acc[m][3] = MFMA(a1[m], c3, acc[m][3]);
        }
        __builtin_amdgcn_s_setprio(0);
    }

#pragma unroll
    for (int m = 0; m < 8; ++m) {
#pragma unroll
        for (int n = 0; n < 4; ++n) {
            int gc = n0 + wn * 64 + n * 16 + lr;
#pragma unroll
            for (int j = 0; j < 4; ++j) {
                int gr = m0 + wm * 128 + m * 16 + lh * 4 + j;
                if (gr >= M) continue;
                float val = acc[m][n][j];
                if (MODE == 0) {
                    short* o = (short*)(nsel == 0 ? o0 : (nsel == 1 ? o1 : o2));
                    o[(size_t)gr * 1024 + gc] = f2bf(val);
                } else {
                    short* P = (short*)o0 + (size_t)blockIdx.z * (size_t)seg;
                    P[(size_t)gr * 1024 + gc] = f2bf(val);
                }
            }
        }
    }
}

// ---------------------------------------------------------------- fused FFN1 GEMM: 256 main blocks (gemm8p body)
// + 32 trailing small blocks (gemm_bt body, M=32 sum-token path; both paths'
// buffers fully disjoint — audited).
__global__ __launch_bounds__(512, 2) void gemm8pf2(
    const short* __restrict__ A, int M, int K, int klen,
    const short* __restrict__ B0, const float* __restrict__ bias,
    void* __restrict__ o0,
    const short* __restrict__ sA, const short* __restrict__ sB,
    const float* __restrict__ sBias, void* __restrict__ sOut)
{
    const int tid = threadIdx.x;
    const int id = blockIdx.x;

    __shared__ __align__(16) short L[2 * 32768];

    if (id >= 256) {
        // small path: M=32, N=4096 (32 tiles), K=1024
        const int sid = id - 256;
        const int n0 = sid * 128;
        const int Ks = 1024;
        const int w = tid >> 6, l = tid & 63;
        const int lr = l & 15, lh = l >> 4;
        const bool act = (tid < 256);
        const int wr = (w >> 1) * 64, wc = (w & 1) * 64;
        short* As_s = L;
        short* Bs_s = L + 8192;
        const int srow = (w & 3) * 32 + (l >> 2);
        const int scol = (((l & 3) ^ ((l >> 3) & 3))) * 8;
        int ar0 = srow;      if (ar0 > 31) ar0 = 31;
        int ar1 = srow + 16; if (ar1 > 31) ar1 = 31;
        const short* ga0 = sA + (size_t)ar0 * Ks + scol;
        const short* ga1 = sA + (size_t)ar1 * Ks + scol;
        const short* gb0 = sB + (size_t)(n0 + srow) * Ks + scol;
        const short* gb1 = sB + (size_t)(n0 + srow + 16) * Ks + scol;
        const int lofs = ((w & 3) * 32) * 32;
        const int cbrd = (lh ^ ((lr >> 1) & 3)) * 8;

        f32x4 acc[4][4];
#pragma unroll
        for (int m = 0; m < 4; ++m)
#pragma unroll
            for (int n = 0; n < 4; ++n) acc[m][n] = (f32x4){0.f, 0.f, 0.f, 0.f};

        auto STAGE = [&](int j, int buf) {
            const int k0 = j * 32;
            short* a = As_s + buf * 4096 + lofs;
            short* b = Bs_s + buf * 4096 + lofs;
            gll16(ga0 + k0, a);
            gll16(ga1 + k0, a + 512);
            gll16(gb0 + k0, b);
            gll16(gb1 + k0, b + 512);
        };

        const int nk = Ks >> 5;
        if (act) STAGE(0, 0);
        for (int t = 0; t < nk; ++t) {
            __syncthreads();
            const int cur = (t & 1);
            if (act) {
                if (t + 1 < nk) STAGE(t + 1, cur ^ 1);
                const int co = cur << 12;
                short8 af[4], bfr[4];
#pragma unroll
                for (int m = 0; m < 4; ++m)
                    af[m] = *(const short8*)(As_s + co + (wr + m * 16 + lr) * 32 + cbrd);
#pragma unroll
                for (int n = 0; n < 4; ++n)
                    bfr[n] = *(const short8*)(Bs_s + co + (wc + n * 16 + lr) * 32 + cbrd);
#pragma unroll
                for (int m = 0; m < 4; ++m)
#pragma unroll
                    for (int n = 0; n < 4; ++n)
                        acc[m][n] = MFMA(af[m], bfr[n], acc[m][n]);
            }
        }

        if (act) {
#pragma unroll
            for (int m = 0; m < 4; ++m) {
#pragma unroll
                for (int n = 0; n < 4; ++n) {
                    int gc = n0 + wc + n * 16 + lr;
#pragma unroll
                    for (int j = 0; j < 4; ++j) {
                        int gr = wr + m * 16 + lh * 4 + j;
                        if (gr >= 32) continue;
                        float val = acc[m][n][j] + sBias[gc];
                        val = val > 0.f ? val : 0.f;
                        ((short*)sOut)[(size_t)gr * 4096 + gc] = f2bf(val);
                    }
                }
            }
        }
        return;
    }

    // main path: gemm8p MODE-2 body, bx = id&15, ntile = id>>4
    const int w = tid >> 6, l = tid & 63;
    const int lr = l & 15, lh = l >> 4;
    const int bx = id & 15, ntile = id >> 4;
    const int m0 = bx * 256;
    const int n0 = ntile * 256;
    const int wm = w >> 2, wn = w & 3;

    const int srow = tid >> 2;
    const int scb  = (tid & 3) ^ ((srow >> 1) & 3);
    int ar0 = m0 + srow;        if (ar0 > M - 1) ar0 = M - 1;
    int ar1 = m0 + srow + 128;  if (ar1 > M - 1) ar1 = M - 1;
    const short* gA0 = A + (size_t)ar0 * K + scb * 8;
    const short* gA1 = A + (size_t)ar1 * K + scb * 8;
    const short* gB0 = B0 + (size_t)(n0 + srow) * K + scb * 8;
    const short* gB1 = B0 + (size_t)(n0 + srow + 128) * K + scb * 8;
    const int wofs = w * 512;
    const int cbrd = (lh ^ ((lr >> 1) & 3)) * 8;

    f32x4 acc[8][4];
#pragma unroll
    for (int m = 0; m < 8; ++m)
#pragma unroll
        for (int n = 0; n < 4; ++n) acc[m][n] = (f32x4){0.f, 0.f, 0.f, 0.f};

    auto STG = [&](int tt, int s, bool isB) {
        const int off = (tt & 1) * 32768 + s * 16384 + (isB ? 8192 : 0);
        const int gk  = tt * 64 + s * 32;
        if (!isB) {
            gll16(gA0 + gk, L + off + wofs);
            gll16(gA1 + gk, L + off + 4096 + wofs);
        } else {
            gll16(gB0 + gk, L + off + wofs);
            gll16(gB1 + gk, L + off + 4096 + wofs);
        }
    };

    const int nt = klen >> 6;
    STG(0, 0, false); STG(0, 0, true); STG(0, 1, false); STG(0, 1, true);

    const int arow = wm * 128, brow = wn * 64;

    for (int t = 0; t < nt; ++t) {
        const int buf = (t & 1) * 32768;
        const short* LA0 = L + buf;
        const short* LB0 = L + buf + 8192;
        const short* LA1 = L + buf + 16384;
        const short* LB1 = L + buf + 24576;

        asm volatile("s_waitcnt vmcnt(4)" ::: "memory");
        __builtin_amdgcn_s_barrier();
        asm volatile("" ::: "memory");
        if (t + 1 < nt) STG(t + 1, 0, false);
        short8 a0[8];
#pragma unroll
        for (int m = 0; m < 8; ++m)
            a0[m] = *(const short8*)(LA0 + (arow + m * 16 + lr) * 32 + cbrd);
        short8 b0 = *(const short8*)(LB0 + (brow + lr) * 32 + cbrd);
        short8 b1 = *(const short8*)(LB0 + (brow + 16 + lr) * 32 + cbrd);
        __builtin_amdgcn_s_setprio(1);
#pragma unroll
        for (int m = 0; m < 8; ++m) {
            acc[m][0] = MFMA(a0[m], b0, acc[m][0]);
            acc[m][1] = MFMA(a0[m], b1, acc[m][1]);
        }
        __builtin_amdgcn_s_setprio(0);

        if (t + 1 < nt) asm volatile("s_waitcnt vmcnt(2)" ::: "memory");
        else            asm volatile("s_waitcnt vmcnt(0)" ::: "memory");
        __builtin_amdgcn_s_barrier();
        asm volatile("" ::: "memory");
        if (t + 1 < nt) STG(t + 1, 0, true);
        short8 b2 = *(const short8*)(LB0 + (brow + 32 + lr) * 32 + cbrd);
        short8 b3 = *(const short8*)(LB0 + (brow + 48 + lr) * 32 + cbrd);
        __builtin_amdgcn_s_setprio(1);
#pragma unroll
        for (int m = 0; m < 8; ++m) {
            acc[m][2] = MFMA(a0[m], b2, acc[m][2]);
            acc[m][3] = MFMA(a0[m], b3, acc[m][3]);
        }
        __builtin_amdgcn_s_setprio(0);
        short8 a1[8];
#pragma unroll
        for (int m = 0; m < 8; ++m)
            a1[m] = *(const short8*)(LA1 + (arow + m * 16 + lr) * 32 + cbrd);
        short8 c0 = *(const short8*)(LB1 + (brow + lr) * 32 + cbrd);
        short8 c1 = *(const short8*)(LB1 + (brow + 16 + lr) * 32 + cbrd);

        __builtin_amdgcn_s_barrier();
        asm volatile("" ::: "memory");
        if (t + 1 < nt) STG(t + 1, 1, false);
        __builtin_amdgcn_s_setprio(1);
#pragma unroll
        for (int m = 0; m < 8; ++m) {
            acc[m][0] = MFMA(a1[m], c0, acc[m][0]);
            acc[m][1] = MFMA(a1[m], c1, acc[m][1]);
        }
        __builtin_amdgcn_s_setprio(0);
        short8 c2 = *(const short8*)(LB1 + (brow + 32 + lr) * 32 + cbrd);
        short8 c3 = *(const short8*)(LB1 + (brow + 48 + lr) * 32 + cbrd);

        __builtin_amdgcn_s_barrier();
        asm volatile("" ::: "memory");
        if (t + 1 < nt) STG(t + 1, 1, true);
        __builtin_amdgcn_s_setprio(1);
#pragma unroll
        for (int m = 0; m < 8; ++m) {
            acc[m][2] = MFMA(a1[m], c2, acc[m][2]);
            acc[m][3] = MFMA(a1[m], c3, acc[m][3]);
        }
        __builtin_amdgcn_s_setprio(0);
    }

#pragma unroll
    for (int m = 0; m < 8; ++m) {
#pragma unroll
        for (int n = 0; n < 4; ++n) {
            int gc = n0 + wn * 64 + n * 16 + lr;
#pragma unroll
            for (int j = 0; j < 4; ++j) {
                int gr = m0 + wm * 128 + m * 16 + lh * 4 + j;
                if (gr >= M) continue;
                float val = acc[m][n][j] + bias[gc];
                val = val > 0.f ? val : 0.f;
                ((short*)o0)[(size_t)gr * 4096 + gc] = f2bf(val);
            }
        }
    }
}

// ---------------------------------------------------------------- GEMM 128x128 (FFN2-sum split-K, f32 partials)
__global__ __launch_bounds__(256) void gemm_bt1(
    const short* __restrict__ A, int M, int K, int klen,
    const short* __restrict__ B0,
    void* __restrict__ o0, int seg)
{
    const int tid = threadIdx.x;
    const int w = tid >> 6, l = tid & 63;
    const int lr = l & 15, lh = l >> 4;
    const int m0 = blockIdx.x * 128;
    const int n0 = blockIdx.y * 128;
    const short* B = B0;
    const int wr = (w >> 1) * 64, wc = (w & 1) * 64;
    const int kbase = blockIdx.z * klen;

    __shared__ __align__(16) short As[2 * 4096];
    __shared__ __align__(16) short Bs[2 * 4096];

    const int srow = w * 32 + (l >> 2);
    const int scol = (((l & 3) ^ ((l >> 3) & 3))) * 8;
    int ar0 = m0 + srow;      if (ar0 > M - 1) ar0 = M - 1;
    int ar1 = m0 + srow + 16; if (ar1 > M - 1) ar1 = M - 1;
    const short* ga0 = A + (size_t)ar0 * K + scol + kbase;
    const short* ga1 = A + (size_t)ar1 * K + scol + kbase;
    const short* gb0 = B + (size_t)(n0 + srow) * K + scol + kbase;
    const short* gb1 = B + (size_t)(n0 + srow + 16) * K + scol + kbase;
    const int lofs = (w * 32) * 32;
    const int cbrd = (lh ^ ((lr >> 1) & 3)) * 8;

    f32x4 acc[4][4];
#pragma unroll
    for (int m = 0; m < 4; ++m)
#pragma unroll
        for (int n = 0; n < 4; ++n) acc[m][n] = (f32x4){0.f, 0.f, 0.f, 0.f};

    auto STAGE = [&](int j, int buf) {
        const int k0 = j * 32;
        short* a = As + buf * 4096 + lofs;
        short* b = Bs + buf * 4096 + lofs;
        gll16(ga0 + k0, a);
        gll16(ga1 + k0, a + 512);
        gll16(gb0 + k0, b);
        gll16(gb1 + k0, b + 512);
    };

    const int nk = klen >> 5;
    STAGE(0, 0);
    for (int t = 0; t < nk; ++t) {
        __syncthreads();
        const int cur = (t & 1);
        if (t + 1 < nk) STAGE(t + 1, cur ^ 1);
        const int co = cur << 12;
        short8 af[4], bfr[4];
#pragma unroll
        for (int m = 0; m < 4; ++m)
            af[m] = *(const short8*)(As + co + (wr + m * 16 + lr) * 32 + cbrd);
#pragma unroll
        for (int n = 0; n < 4; ++n)
            bfr[n] = *(const short8*)(Bs + co + (wc + n * 16 + lr) * 32 + cbrd);
#pragma unroll
        for (int m = 0; m < 4; ++m)
#pragma unroll
            for (int n = 0; n < 4; ++n)
                acc[m][n] = MFMA(af[m], bfr[n], acc[m][n]);
    }

#pragma unroll
    for (int m = 0; m < 4; ++m) {
#pragma unroll
        for (int n = 0; n < 4; ++n) {
            int gc = n0 + wc + n * 16 + lr;
#pragma unroll
            for (int j = 0; j < 4; ++j) {
                int gr = m0 + wr + m * 16 + lh * 4 + j;
                if (gr >= M) continue;
                float* P = (float*)o0 + (size_t)blockIdx.z * (size_t)seg;
                P[(size_t)gr * 1024 + gc] = acc[m][n][j];
            }
        }
    }
}

// ---------------------------------------------------------------- merged split-K reduce
__global__ __launch_bounds__(256) void reduce_all(
    const float* __restrict__ x1, const short* __restrict__ Pf2,
    const float* __restrict__ Psum,
    const float* __restrict__ rbias, const float* __restrict__ sbias,
    float* __restrict__ out)
{
    if (blockIdx.x < 4096) {
        size_t i = ((size_t)blockIdx.x * 256 + threadIdx.x) * 4;
        int gr = (int)(i >> 10), c = (int)(i & 1023);
        size_t g = (size_t)((gr >> 11) * 2064 + 16 + (gr & 2047)) * 1024 + c;
        float4 r  = *(const float4*)(x1 + g);
        float4 bb = *(const float4*)(rbias + c);
        float ox = r.x + bb.x, oy = r.y + bb.y, oz = r.z + bb.z, ow = r.w + bb.w;
#pragma unroll
        for (int z = 0; z < 4; ++z) {
            short4 p = *(const short4*)(Pf2 + (size_t)z * 4194304 + i);
            ox += bf2f(p.x); oy += bf2f(p.y); oz += bf2f(p.z); ow += bf2f(p.w);
        }
        float4 o; o.x = ox; o.y = oy; o.z = oz; o.w = ow;
        *(float4*)(out + g) = o;
        return;
    }
    int i = ((blockIdx.x - 4096) * 256 + threadIdx.x) * 4;
    int gr = i >> 10, c = i & 1023;
    size_t g = (size_t)((gr >> 4) * 2064 + (gr & 15)) * 1024 + c;
    float4 r  = *(const float4*)(x1 + g);
    float4 bb = *(const float4*)(sbias + c);
    float ox = r.x + bb.x, oy = r.y + bb.y, oz = r.z + bb.z, ow = r.w + bb.w;
#pragma unroll
    for (int s = 0; s < 16; ++s) {
        float4 p = *(const float4*)(Psum + s * 32768 + i);
        ox += p.x; oy += p.y; oz += p.z; ow += p.w;
    }
    float4 o; o.x = ox; o.y = oy; o.z = oz; o.w = ow;
    *(float4*)(out + g) = o;
}

// ---------------------------------------------------------------- fused attention (reg blocks + sum blocks)
__global__ __launch_bounds__(256) void attn_all(
    const short* __restrict__ q, const short* __restrict__ k,
    const short* __restrict__ v, short* __restrict__ ctx)
{
    __shared__ __align__(16) short Pl[128 * 168];
    __shared__ __align__(16) short Vt[64 * 168];
    short* Kl = Pl;

    const int tid = threadIdx.x;
    const int blk = blockIdx.x;

    if (blk >= 512) {
        const int g = tid >> 6, l = tid & 63;
        const int idx = (blk - 512) * 4 + g;
        const int b = idx >> 8, h = (idx >> 4) & 15, s = idx & 15;
        const int hc = h * 64;
        size_t qrow = (size_t)b * 2064 + s;
        float* qv = ((float*)Pl) + g * 64;
        float* pp = ((float*)Pl) + 256 + g * 192;
        qv[l] = bf2f(q[qrow * 1024 + hc + l]);
        __syncthreads();
        float sc[3];
#pragma unroll
        for (int i = 0; i < 3; ++i) {
            int j = l + i * 64;
            float t = -1e30f;
            if (j < 144 && (j >= 16 || j <= s)) {
                size_t kr = (j < 16) ? ((size_t)b * 2064 + j)
                                     : ((size_t)b * 2064 + 16 + (size_t)s * 128 + (j - 16));
                const short* kp = k + kr * 1024 + hc;
                float acc = 0.f;
                for (int d = 0; d < 64; ++d) acc += qv[d] * bf2f(kp[d]);
                t = acc * 0.125f;
            }
            sc[i] = t;
        }
        float mx = fmaxf(sc[0], fmaxf(sc[1], sc[2]));
#pragma unroll
        for (int off = 1; off < 64; off <<= 1) mx = fmaxf(mx, __shfl_xor(mx, off));
        float sm = 0.f;
#pragma unroll
        for (int i = 0; i < 3; ++i) {
            float ex = (sc[i] > -1e29f) ? __expf(sc[i] - mx) : 0.f;
            pp[l + i * 64] = ex;
            sm += ex;
        }
#pragma unroll
        for (int off = 1; off < 64; off <<= 1) sm += __shfl_xor(sm, off);
        __syncthreads();
        float invs = 1.0f / sm;
        float acc = 0.f;
        for (int j = 0; j < 144; ++j) {
            float pj = pp[j];
            size_t vr = (j < 16) ? ((size_t)b * 2064 + j)
                                 : ((size_t)b * 2064 + 16 + (size_t)s * 128 + (j - 16));
            acc += pj * bf2f(v[vr * 1024 + hc + l]);
        }
        ctx[qrow * 1024 + hc + l] = f2bf(acc * invs);
        return;
    }

    const int w = tid >> 6, l = tid & 63, lr = l & 15, lh = l >> 4;
    const int c = blk & 15, h = (blk >> 4) & 15, b = blk >> 8;
    const int hc = h * 64;
    const size_t rowq0 = (size_t)b * 2064 + 16 + (size_t)c * 128;

    for (int ch = tid; ch < 1152; ch += 256) {
        int row = ch >> 3, kk = (ch & 7) << 3;
        size_t grow = (row < 16) ? ((size_t)b * 2064 + row) : (rowq0 + row - 16);
        *(int4*)(Kl + row * 72 + kk) = *(const int4*)(k + grow * 1024 + hc + kk);
    }
    for (int ch = tid; ch < 1152; ch += 256) {
        int j = ch % 144, db = ch / 144;
        size_t grow = (j < 16) ? ((size_t)b * 2064 + j) : (rowq0 + j - 16);
        short8 dv = *(const short8*)(v + grow * 1024 + hc + db * 8);
#pragma unroll
        for (int i = 0; i < 8; ++i) Vt[(db * 8 + i) * 168 + j] = dv[i];
    }
    for (int idx = tid; idx < 1024; idx += 256) {
        int d = idx >> 4, jj = 144 + (idx & 15);
        Vt[d * 168 + jj] = 0;
    }
    __syncthreads();

    short8 qf[2][2];
#pragma unroll
    for (int m = 0; m < 2; ++m) {
        size_t grow = rowq0 + w * 32 + m * 16 + lr;
#pragma unroll
        for (int ks = 0; ks < 2; ++ks)
            qf[m][ks] = *(const short8*)(q + grow * 1024 + hc + ks * 32 + lh * 8);
    }

    f32x4 s[2][9];
#pragma unroll
    for (int m = 0; m < 2; ++m)
#pragma unroll
        for (int n = 0; n < 9; ++n) s[m][n] = (f32x4){0.f, 0.f, 0.f, 0.f};
    __builtin_amdgcn_s_setprio(1);
#pragma unroll
    for (int n = 0; n < 9; ++n) {
        const short* kr = Kl + (n * 16 + lr) * 72;
        short8 k0 = *(const short8*)(kr + lh * 8);
        short8 k1 = *(const short8*)(kr + 32 + lh * 8);
        s[0][n] = MFMA(qf[0][0], k0, s[0][n]);
        s[0][n] = MFMA(qf[0][1], k1, s[0][n]);
        s[1][n] = MFMA(qf[1][0], k0, s[1][n]);
        s[1][n] = MFMA(qf[1][1], k1, s[1][n]);
    }
    __builtin_amdgcn_s_setprio(0);

    float inv_[2][4];
#pragma unroll
    for (int m = 0; m < 2; ++m) {
#pragma unroll
        for (int j = 0; j < 4; ++j) {
            int p = w * 32 + m * 16 + lh * 4 + j;
            float best = -1e30f;
            float e[9];
#pragma unroll
            for (int n = 0; n < 9; ++n) {
                int kk = n * 16 + lr;
                bool vis = (kk < 16) ? (kk < c) : (kk - 16 <= p);
                float val = vis ? s[m][n][j] * 0.125f : -1e30f;
                e[n] = val;
                best = fmaxf(best, val);
            }
#pragma unroll
            for (int off = 1; off < 16; off <<= 1) best = fmaxf(best, __shfl_xor(best, off));
            float sm = 0.f;
#pragma unroll
            for (int n = 0; n < 9; ++n) {
                float ex = __expf(e[n] - best);
                s[m][n][j] = ex;
                sm += ex;
            }
#pragma unroll
            for (int off = 1; off < 16; off <<= 1) sm += __shfl_xor(sm, off);
            inv_[m][j] = 1.0f / sm;
        }
    }

    __syncthreads();
#pragma unroll
    for (int m = 0; m < 2; ++m)
#pragma unroll
        for (int n = 0; n < 9; ++n)
#pragma unroll
            for (int j = 0; j < 4; ++j)
                Pl[(w * 32 + m * 16 + lh * 4 + j) * 168 + n * 16 + lr] = f2bf(s[m][n][j]);
    for (int idx = l; idx < 512; idx += 64) {
        int rr = idx >> 4, kkp = 144 + (idx & 15);
        Pl[(w * 32 + rr) * 168 + kkp] = 0;
    }
    __syncthreads();

    f32x4 dacc[2][4];
#pragma unroll
    for (int m = 0; m < 2; ++m)
#pragma unroll
        for (int n = 0; n < 4; ++n) dacc[m][n] = (f32x4){0.f, 0.f, 0.f, 0.f};
#pragma unroll
    for (int ks = 0; ks < 5; ++ks) {
        int kk0 = ks * 32;
        short8 pa[2];
#pragma unroll
        for (int m = 0; m < 2; ++m)
            pa[m] = *(const short8*)(Pl + (w * 32 + m * 16 + lr) * 168 + kk0 + lh * 8);
        __builtin_amdgcn_s_setprio(1);
#pragma unroll
        for (int n = 0; n < 4; ++n) {
            short8 vb = *(const short8*)(Vt + (n * 16 + lr) * 168 + kk0 + lh * 8);
            dacc[0][n] = MFMA(pa[0], vb, dacc[0][n]);
            dacc[1][n] = MFMA(pa[1], vb, dacc[1][n]);
        }
        __builtin_amdgcn_s_setprio(0);
    }

#pragma unroll
    for (int m = 0; m < 2; ++m)
#pragma unroll
        for (int n = 0; n < 4; ++n)
#pragma unroll
            for (int j = 0; j < 4; ++j) {
                int p = w * 32 + m * 16 + lh * 4 + j;
                ctx[(rowq0 + p) * 1024 + hc + n * 16 + lr] = f2bf(dacc[m][n][j] * inv_[m][j]);
            }
}

// ---------------------------------------------------------------- launch
extern "C" void kernel_launch(void* const* d_in, const int* in_sizes, int n_in,
                              void* d_out, int out_size, void* d_ws, size_t ws_size,
                              hipStream_t stream) {
    const float* x    = (const float*)d_in[0];
    const float* wq   = (const float*)d_in[1];
    const float* wk   = (const float*)d_in[2];
    const float* wv   = (const float*)d_in[3];
    const float* wo   = (const float*)d_in[4];
    const float* lsg  = (const float*)d_in[5];
    const float* lsb  = (const float*)d_in[6];
    const float* lrg  = (const float*)d_in[7];
    const float* lrb  = (const float*)d_in[8];
    const float* sf1w = (const float*)d_in[9];
    const float* sf1b = (const float*)d_in[10];
    const float* sf2w = (const float*)d_in[11];
    const float* sf2b = (const float*)d_in[12];
    const float* rf1w = (const float*)d_in[13];
    const float* rf1b = (const float*)d_in[14];
    const float* rf2w = (const float*)d_in[15];
    const float* rf2b = (const float*)d_in[16];
    const float* fsg  = (const float*)d_in[17];
    const float* fsb  = (const float*)d_in[18];
    const float* frg  = (const float*)d_in[19];
    const float* frb  = (const float*)d_in[20];
    float* out = (float*)d_out;

    char* ws = (char*)d_ws;
    // ---- byte-range liveness map (per-dispatch audited) ----
    short* wbf   = (short*)ws;
    short* wq_b  = wbf;
    short* wk_b  = wbf + 1048576;
    short* wv_b  = wbf + 2097152;
    short* wo_b  = wbf + 3145728;
    short* f1s_b = wbf + 4194304;
    short* f2s_b = wbf + 8388608;               // read step 7 (BEFORE Pf2 overwrite, step 8)
    short* f1r_b = wbf + 12582912;
    short* f2r_b = wbf + 16777216;
    short* h_all = (short*)(ws + 41943040);
    short* qb   = (short*)(ws + 50397184);
    short* kb   = qb + 4227072;
    short* vb   = kb + 4227072;
    short* ctxb = vb + 4227072;                 // [75759616, 84213760)
    short* Pwo  = (short*)(ws + 41943040);
    float* x1   = (float*)(ws + 84213760);
    short* h2_reg = (short*)ws;                 // [0, 8388608)
    short* h2_sum = (short*)(ws + 75759616);
    short* f1_reg = (short*)(ws + 41943040);
    short* f1_sum = (short*)(ws + 75825152);
    float* Psum   = (float*)(ws + 76087296);    // over dead ctx, live 7 -> reduce
    short* Pf2    = (short*)ws;                 // [0, 33554432), written step 8 (f2s_b dead)

    // 1. fused weights->bf16 + pre-attn LN
    cvt_ln<<<24608, 256, 0, stream>>>(wq, wk, wv, wo, sf1w, sf2w, rf1w, rf2w, wbf,
                                      x, lsg, lsb, lrg, lrb, h_all);
    // 2. fused QKV
    gemm8p<0><<<dim3(17, 12, 1), 512, 0, stream>>>(h_all, 4128, 1024, 1024,
        wq_b, wk_b, wv_b, nullptr, qb, kb, vb, 0);
    // 3. fused attention (chunk + sum-token)
    attn_all<<<640, 256, 0, stream>>>(qb, kb, vb, ctxb);
    // 4. W_O split-K=2 -> Pwo
    gemm8p<3><<<dim3(17, 4, 2), 512, 0, stream>>>(ctxb, 4128, 1024, 512,
        wo_b, nullptr, nullptr, nullptr, Pwo, nullptr, nullptr, 4227072);
    // 5. fused WO-reduce + pre-FFN LN
    ln_k1<<<4128, 256, 0, stream>>>(x, Pwo, x1, fsg, fsb, frg, frb,
                                    h2_sum, h2_reg);
    // 6. fused FFN1 (256 main reg-blocks + 32 sum-blocks; disjoint buffers)
    gemm8pf2<<<288, 512, 0, stream>>>(h2_reg, 4096, 1024, 1024,
        f1r_b, rf1b, f1_reg, h2_sum, f1s_b, sf1b, f1_sum);
    // 7. FFN2-sum split-K=16 -> Psum (reads f2s_b BEFORE step 8 overwrites it)
    gemm_bt1<<<dim3(1, 8, 16), 256, 0, stream>>>(f1_sum, 32, 4096, 256,
        f2s_b, Psum, 32768);
    // 8. FFN2-reg split-K=4 -> Pf2
    gemm8p<3><<<dim3(16, 4, 4), 512, 0, stream>>>(f1_reg, 4096, 4096, 1024,
        f2r_b, nullptr, nullptr, nullptr, Pf2, nullptr, nullptr, 4194304);
    // 9. merged reduce -> out
    reduce_all<<<4128, 256, 0, stream>>>(x1, Pf2, Psum, rf2b, sf2b, out);
}